// Round 22
// baseline (1614.732 us; speedup 1.0000x reference)
//
#include <hip/hip_runtime.h>
#include <math.h>

#define DEV __device__ __forceinline__

typedef __attribute__((ext_vector_type(8))) short bf8_t;   // 8 x bf16 (4 VGPR)
typedef __attribute__((ext_vector_type(4))) float f4_t;    // MFMA acc
typedef unsigned short us;

DEV float sigm_f(float v) { return 1.0f / (1.0f + __expf(-v)); }
DEV float tanh_f(float v) { return fmaf(-2.0f, 1.0f / (1.0f + __expf(2.0f * v)), 1.0f); }
DEV float gelu_f(float v) {
  float u = 0.79788456080f * fmaf(0.044715f * v * v, v, v);
  return 0.5f * v * (1.0f + tanh_f(u));
}
DEV unsigned short f2bf(float f) {            // RNE float->bf16
  unsigned u = __float_as_uint(f);
  u = (u + 0x7FFFu + ((u >> 16) & 1u)) >> 16;
  return (unsigned short)u;
}
DEV void astore(unsigned* p, unsigned v) {
  __hip_atomic_store(p, v, __ATOMIC_RELAXED, __HIP_MEMORY_SCOPE_AGENT);
}

// ---------------------------------------------------------------------------
// Fused weight prep: conv weights + misc + el/dl. One launch.
// ---------------------------------------------------------------------------
DEV void prep_norm(int li, const float* w, us* wb, int CIN) {
  int ci = li % CIN;
  int r  = li / CIN;
  int kw = r % 3; r /= 3;
  int kh = r % 3;
  int co = r / 3;
  wb[li] = f2bf(w[((co * CIN + ci) * 3 + kh) * 3 + kw]);
}
DEV void prep_par(int li, const float* w, us* wb, int COUT, int CIN) {
  const int TAPORD[9] = {4, 3, 5, 1, 7, 0, 2, 6, 8};
  int ci = li % CIN;
  int r  = li / CIN;
  int ti = r % 9;
  int co = r / 9;
  int tap = TAPORD[ti];
  int kh = tap / 3, kw = tap % 3;
  wb[li] = f2bf(w[((ci * COUT + co) * 3 + (2 - kh)) * 3 + (2 - kw)]);
}

__global__ __launch_bounds__(256) void prep_all_k(
    const float* __restrict__ ec2, const float* __restrict__ ec3,
    const float* __restrict__ ec4, const float* __restrict__ ec5,
    const float* __restrict__ dt1, const float* __restrict__ dc1,
    const float* __restrict__ dt2, const float* __restrict__ dc2,
    us* __restrict__ o_ec2, us* __restrict__ o_ec3,
    us* __restrict__ o_ec4, us* __restrict__ o_ec5,
    us* __restrict__ o_dt1, us* __restrict__ o_dc1,
    us* __restrict__ o_dt2, us* __restrict__ o_dc2,
    const float* __restrict__ Wih, const float* __restrict__ lw,
    const float* __restrict__ lb,  const float* __restrict__ bih,
    us* __restrict__ wih0b, us* __restrict__ lwTb,
    us* __restrict__ lwbp,  float* __restrict__ beff,
    const float* __restrict__ el_w, const float* __restrict__ dl_w,
    us* __restrict__ elWb, us* __restrict__ dlWb)
{
  int idx = blockIdx.x * 256 + threadIdx.x;            // < 2694144
  if (idx < 202752) {
    if (idx < 9216)        prep_norm(idx,          ec2, o_ec2, 32);
    else if (idx < 27648)  prep_norm(idx - 9216,   ec3, o_ec3, 32);
    else if (idx < 64512)  prep_norm(idx - 27648,  ec4, o_ec4, 64);
    else if (idx < 101376) prep_norm(idx - 64512,  ec5, o_ec5, 64);
    else if (idx < 138240) prep_par (idx - 101376, dt1, o_dt1, 64, 64);
    else if (idx < 175104) prep_norm(idx - 138240, dc1, o_dc1, 64);
    else if (idx < 193536) prep_par (idx - 175104, dt2, o_dt2, 32, 64);
    else                   prep_norm(idx - 193536, dc2, o_dc2, 32);
  } else if (idx < 596992) {
    int i2 = idx - 202752;
    if (i2 < 262144) {
      wih0b[i2] = f2bf(Wih[i2]);
    } else if (i2 < 327680) {
      int i = i2 - 262144;
      int n = i & 255, kcol = i >> 8;
      lwTb[i] = f2bf(lw[(size_t)n * 256 + kcol]);
    } else if (i2 < 393216) {
      int i = i2 - 327680;
      lwbp[i] = f2bf(lw[i]);
    } else if (i2 < 394240) {
      int j = i2 - 393216;
      float s = bih[j];
      const float* row = Wih + (size_t)j * 256;
      for (int n = 0; n < 256; ++n) s = fmaf(row[n], lb[n], s);
      beff[j] = s;
    }
  } else {
    int i3 = idx - 596992;
    if (i3 < 1048576) {
      int kn = i3 & 4095, n = i3 >> 12;
      elWb[i3] = f2bf(el_w[(size_t)n * 4096 + ((kn & 63) * 64 + (kn >> 6))]);
    } else {
      int i = i3 - 1048576;
      int k = i & 255, nout = i >> 8;
      dlWb[i] = f2bf(dl_w[(size_t)((nout & 63) * 64 + (nout >> 6)) * 256 + k]);
    }
  }
}

// ---------------------------------------------------------------------------
// ec1: x frames ONLY (512 images)
// ---------------------------------------------------------------------------
__global__ __launch_bounds__(256) void ec1_k(
    const float* __restrict__ x,
    const float* __restrict__ w, const float* __restrict__ bias,
    us* __restrict__ out)
{
  __shared__ float sw[288];
  __shared__ float sb[32];
  for (int i = threadIdx.x; i < 288; i += 256) sw[i] = w[i];
  if (threadIdx.x < 32) sb[threadIdx.x] = bias[threadIdx.x];
  __syncthreads();
  int idx = blockIdx.x * 256 + threadIdx.x;     // < 512*32*32
  int ox = idx & 31, oy = (idx >> 5) & 31, n = idx >> 10;   // n 0..511
  const float* ip = x + (size_t)n * 4096;
  float pv[9];
#pragma unroll
  for (int kh = 0; kh < 3; ++kh) {
    int iy = oy * 2 + kh - 1;
#pragma unroll
    for (int kw = 0; kw < 3; ++kw) {
      int ix = ox * 2 + kw - 1;
      pv[kh * 3 + kw] = ((unsigned)iy < 64u && (unsigned)ix < 64u) ? ip[iy * 64 + ix] : 0.f;
    }
  }
  us u[32];
#pragma unroll
  for (int co = 0; co < 32; ++co) {
    float a = sb[co];
#pragma unroll
    for (int i = 0; i < 9; ++i) a = fmaf(pv[i], sw[co * 9 + i], a);
    u[co] = f2bf(gelu_f(a));
  }
  us* op = out + (size_t)idx * 32;
#pragma unroll
  for (int p = 0; p < 4; ++p) {
    uint4 v;
    v.x = u[p*8+0] | (u[p*8+1] << 16);
    v.y = u[p*8+2] | (u[p*8+3] << 16);
    v.z = u[p*8+4] | (u[p*8+5] << 16);
    v.w = u[p*8+6] | (u[p*8+7] << 16);
    *(uint4*)&op[p * 8] = v;
  }
}

// ---------------------------------------------------------------------------
// Conv tile device fn (odd LDS stride). Trailing __syncthreads.
// ---------------------------------------------------------------------------
template<int CIN, int COUT, int HIN, int WIN, int TH, int TW, int MODE>
DEV void convmf_tile(const us* __restrict__ in, const us* __restrict__ wb,
                     const float* __restrict__ bias, us* __restrict__ out,
                     int vb, int nofs, us* lds)
{
  constexpr int HO  = (MODE == 1) ? HIN / 2 : HIN;
  constexpr int WO  = (MODE == 1) ? WIN / 2 : WIN;
  constexpr int TIH = (MODE == 1) ? 2 * TH + 1 : TH + 2;
  constexpr int TIW = (MODE == 1) ? 2 * TW + 1 : TW + 2;
  constexpr int TIWP = (TIW & 1) ? TIW : TIW + 1;
  constexpr int CG  = CIN / 8;
  constexpr int K   = 9 * CIN;
  constexpr int KS  = K / 32;
  constexpr int NT  = COUT / 16;
  constexpr int MT  = (TH * TW) / 16;
  constexpr int MPW = MT / 4;
  constexpr int TY  = HO / TH, TX = WO / TW;

  const int n = nofs + vb / (TY * TX);
  const int trem = vb % (TY * TX);
  const int ty0 = (trem / TX) * TH, tx0 = (trem % TX) * TW;

  constexpr int ENT = TIH * TIW * CG;
  for (int e = threadIdx.x; e < ENT; e += 256) {
    int txx = e % TIW;
    int rr  = e / TIW;
    int cg  = rr % CG;
    int tyy = rr / CG;
    int iy, ix; bool ok;
    if (MODE == 0) {
      iy = ty0 + tyy - 1; ix = tx0 + txx - 1;
      ok = (unsigned)iy < (unsigned)HIN && (unsigned)ix < (unsigned)WIN;
    } else {
      iy = 2 * ty0 + tyy - 1; ix = 2 * tx0 + txx - 1;
      ok = (unsigned)iy < (unsigned)HIN && (unsigned)ix < (unsigned)WIN;
    }
    int4 val = {0, 0, 0, 0};
    if (ok) val = *(const int4*)&in[(((size_t)n * HIN + iy) * WIN + ix) * CIN + cg * 8];
    *(int4*)&lds[(size_t)((tyy * CG + cg) * TIWP + txx) * 8] = val;
  }
  __syncthreads();

  const int lane = threadIdx.x & 63, wv = threadIdx.x >> 6;
  const int l15 = lane & 15, l4 = lane >> 4;

  f4_t acc[MPW][NT] = {};
  for (int ks = 0; ks < KS; ++ks) {
    const int tap = (ks * 32) / CIN;
    const int kh = tap / 3, kw = tap % 3;
    const int cb = ((ks * 32) % CIN) / 8 + l4;
    bf8_t bf[NT];
#pragma unroll
    for (int nt = 0; nt < NT; ++nt)
      bf[nt] = *(const bf8_t*)&wb[(size_t)(nt * 16 + l15) * K + ks * 32 + 8 * l4];
#pragma unroll
    for (int mi = 0; mi < MPW; ++mi) {
      int m = (wv * MPW + mi) * 16 + l15;
      int oy = m / TW, ox = m % TW;
      int rt = ((MODE == 1) ? 2 * oy : oy) + kh;
      int ct = ((MODE == 1) ? 2 * ox : ox) + kw;
      bf8_t a = *(const bf8_t*)&lds[(size_t)((rt * CG + cb) * TIWP + ct) * 8];
#pragma unroll
      for (int nt = 0; nt < NT; ++nt)
        acc[mi][nt] = __builtin_amdgcn_mfma_f32_16x16x32_bf16(a, bf[nt], acc[mi][nt], 0, 0, 0);
    }
  }

#pragma unroll
  for (int mi = 0; mi < MPW; ++mi) {
    int mbase = (wv * MPW + mi) * 16;
#pragma unroll
    for (int nt = 0; nt < NT; ++nt) {
      int co = nt * 16 + l15;
      float bv = bias[co];
#pragma unroll
      for (int r = 0; r < 4; ++r) {
        int m = mbase + l4 * 4 + r;
        int oy = m / TW, ox = m % TW;
        float v = acc[mi][nt][r] + bv;
        out[(((size_t)n * HO + ty0 + oy) * WO + (tx0 + ox)) * COUT + co] = f2bf(gelu_f(v));
      }
    }
  }
  __syncthreads();
}

// wrapper kernels (encoder, standalone)
template<int CIN, int COUT, int HIN, int WIN, int TH, int TW, int MODE>
__global__ __launch_bounds__(256) void convmf_k(
    const us* __restrict__ in, const us* __restrict__ wb,
    const float* __restrict__ bias, us* __restrict__ out)
{
  constexpr int TIH = (MODE == 1) ? 2 * TH + 1 : TH + 2;
  constexpr int TIW = (MODE == 1) ? 2 * TW + 1 : TW + 2;
  constexpr int TIWP = (TIW & 1) ? TIW : TIW + 1;
  __shared__ us lds[TIH * TIWP * (CIN / 8) * 8];
  convmf_tile<CIN, COUT, HIN, WIN, TH, TW, MODE>(in, wb, bias, out, blockIdx.x, 0, lds);
}

// ---------------------------------------------------------------------------
// tconv tile device fn (parity waves). Trailing __syncthreads.
// ---------------------------------------------------------------------------
template<int CIN, int COUT, int HIN, int WIN, int SH, int SW>
DEV void tconvp_tile(const us* __restrict__ in, const us* __restrict__ wbp,
                     const float* __restrict__ bias, us* __restrict__ out,
                     int vb, int nofs, us* lds)
{
  constexpr int HO = 2 * HIN, WO = 2 * WIN;
  constexpr int CG = CIN / 8;
  constexpr int TIH = SH + 1, TIW = SW + 1;
  constexpr int NT = COUT / 16;
  constexpr int MPW_P = (SH * SW) / 16;
  constexpr int TY = HIN / SH, TX = WIN / SW;

  const int n = nofs + vb / (TY * TX);
  const int trem = vb % (TY * TX);
  const int toy = trem / TX, tox = trem % TX;
  const int ty0s = toy * SH, tx0s = tox * SW;

  constexpr int ENT = TIH * TIW * CG;
  for (int e = threadIdx.x; e < ENT; e += 256) {
    int txx = e % TIW;
    int rr  = e / TIW;
    int cg  = rr % CG;
    int tyy = rr / CG;
    int iy = ty0s + tyy, ix = tx0s + txx;
    int4 val = {0, 0, 0, 0};
    if (iy < HIN && ix < WIN)
      val = *(const int4*)&in[(((size_t)n * HIN + iy) * WIN + ix) * CIN + cg * 8];
    *(int4*)&lds[(size_t)((tyy * CG + cg) * TIW + txx) * 8] = val;
  }
  __syncthreads();

  const int lane = threadIdx.x & 63, wv = threadIdx.x >> 6;
  const int l15 = lane & 15, l4 = lane >> 4;
  const int dy = wv >> 1, dx = wv & 1;
  const int NXT = 1 + dx;
  const int KS2 = ((1 + dy) * (1 + dx) * CIN) / 32;
  const int koff = (dy ? (dx ? 5 : 3) : (dx ? 1 : 0)) * CIN;

  f4_t acc[MPW_P][NT] = {};
  for (int ks = 0; ks < KS2; ++ks) {
    const int tapi = (ks * 32) / CIN;
    const int cb = ((ks * 32) % CIN) / 8 + l4;
    const int ra = tapi / NXT, rb = tapi % NXT;
    bf8_t bf[NT];
#pragma unroll
    for (int nt = 0; nt < NT; ++nt)
      bf[nt] = *(const bf8_t*)&wbp[(size_t)(nt * 16 + l15) * 9 * CIN + koff + ks * 32 + 8 * l4];
#pragma unroll
    for (int mi = 0; mi < MPW_P; ++mi) {
      int m = mi * 16 + l15;
      int i = m / SW, j = m % SW;
      bf8_t a = *(const bf8_t*)&lds[(size_t)(((i + ra) * CG + cb) * TIW + (j + rb)) * 8];
#pragma unroll
      for (int nt = 0; nt < NT; ++nt)
        acc[mi][nt] = __builtin_amdgcn_mfma_f32_16x16x32_bf16(a, bf[nt], acc[mi][nt], 0, 0, 0);
    }
  }

#pragma unroll
  for (int mi = 0; mi < MPW_P; ++mi) {
#pragma unroll
    for (int nt = 0; nt < NT; ++nt) {
      int co = nt * 16 + l15;
      float bv = bias[co];
#pragma unroll
      for (int r = 0; r < 4; ++r) {
        int m = mi * 16 + l4 * 4 + r;
        int i = m / SW, j = m % SW;
        int orow = 2 * (ty0s + i) + dy, ocol = 2 * (tx0s + j) + dx;
        float v = acc[mi][nt][r] + bv;
        out[(((size_t)n * HO + orow) * WO + ocol) * COUT + co] = f2bf(gelu_f(v));
      }
    }
  }
  __syncthreads();
}

// ---------------------------------------------------------------------------
// MFMA GEMM. OUTMODE 3 = direct frag-swizzled (meffb) write.
// ---------------------------------------------------------------------------
template<int BIASMODE, bool GELU, int OUTMODE>
__global__ __launch_bounds__(256) void gemm16_k(
    const us* __restrict__ A, const us* __restrict__ Bw,
    const float* __restrict__ bias, void* __restrict__ Cv, int M, int N, int K)
{
  const int lane = threadIdx.x & 63, wv = threadIdx.x >> 6;
  const int l15 = lane & 15, l4 = lane >> 4;
  const int mbase = blockIdx.y * 64 + wv * 16;
  const int nbase = blockIdx.x * 64;
  f4_t acc[4] = {};
  for (int k0 = 0; k0 < K; k0 += 32) {
    bf8_t a = *(const bf8_t*)&A[(size_t)(mbase + l15) * K + k0 + 8 * l4];
#pragma unroll
    for (int nt = 0; nt < 4; ++nt) {
      bf8_t b = *(const bf8_t*)&Bw[(size_t)(nbase + nt * 16 + l15) * K + k0 + 8 * l4];
      acc[nt] = __builtin_amdgcn_mfma_f32_16x16x32_bf16(a, b, acc[nt], 0, 0, 0);
    }
  }
#pragma unroll
  for (int nt = 0; nt < 4; ++nt) {
    int col = nbase + nt * 16 + l15;
    float bv = 0.f;
    if (BIASMODE == 0) bv = bias[col];
    if (BIASMODE == 1) bv = bias[(col & 63) * 64 + (col >> 6)];
#pragma unroll
    for (int r = 0; r < 4; ++r) {
      int row = mbase + l4 * 4 + r;
      float v = acc[nt][r] + bv;
      if (GELU) v = gelu_f(v);
      if (OUTMODE == 0)      ((float*)Cv)[(size_t)row * N + col] = v;
      else if (OUTMODE == 1) ((us*)Cv)[(size_t)row * N + col] = f2bf(v);
      else if (OUTMODE == 3) {
        int nt2 = row >> 4, l15d = row & 15;
        int ks2 = col >> 5, l4d = (col >> 3) & 3, e2 = col & 7;
        ((us*)Cv)[(size_t)nt2 * 4096 + ks2 * 512 + (l4d * 16 + l15d) * 8 + e2] = f2bf(v);
      }
    }
  }
}

// el GEMM split-K: M=512, K=4096 in 8 chunks of 512. grid (4,8,8). fp32 partials.
__global__ __launch_bounds__(256) void elgemm_splitk_k(
    const us* __restrict__ A, const us* __restrict__ Bw,
    float* __restrict__ zpart)
{
  const int lane = threadIdx.x & 63, wv = threadIdx.x >> 6;
  const int l15 = lane & 15, l4 = lane >> 4;
  const int mbase = blockIdx.y * 64 + wv * 16;
  const int nbase = blockIdx.x * 64;
  const int kbase = blockIdx.z * 512;
  f4_t acc[4] = {};
  for (int k0 = kbase; k0 < kbase + 512; k0 += 32) {
    bf8_t a = *(const bf8_t*)&A[(size_t)(mbase + l15) * 4096 + k0 + 8 * l4];
#pragma unroll
    for (int nt = 0; nt < 4; ++nt) {
      bf8_t b = *(const bf8_t*)&Bw[(size_t)(nbase + nt * 16 + l15) * 4096 + k0 + 8 * l4];
      acc[nt] = __builtin_amdgcn_mfma_f32_16x16x32_bf16(a, b, acc[nt], 0, 0, 0);
    }
  }
  float* zp = zpart + (size_t)blockIdx.z * 131072;
#pragma unroll
  for (int nt = 0; nt < 4; ++nt) {
    int col = nbase + nt * 16 + l15;
#pragma unroll
    for (int r = 0; r < 4; ++r) {
      int row = mbase + l4 * 4 + r;
      zp[(size_t)row * 256 + col] = acc[nt][r];
    }
  }
}

// combine split-K partials (fixed order = deterministic) + bias.
__global__ __launch_bounds__(256) void zcombine_k(
    const float* __restrict__ zpart, const float* __restrict__ el_b,
    us* __restrict__ zbf, us* __restrict__ ydec)
{
  int idx = blockIdx.x * 256 + threadIdx.x;   // < 131072
  int row = idx >> 8, col = idx & 255;        // row = b*16+tt
  float s = el_b[col];
#pragma unroll
  for (int kc = 0; kc < 8; ++kc) s += zpart[(size_t)kc * 131072 + idx];
  int b = row >> 4, tt = row & 15;
  us v = f2bf(s);
  zbf[(size_t)(tt * 32 + b) * 256 + col] = v;
  ydec[(size_t)(512 + row) * 256 + col] = v;
}

// outs-GEMM tile (pred ydec rows 0..511, permuted): vb in [0,32)
DEV void outsgemm_tile(const us* __restrict__ A, const us* __restrict__ Bw,
                       const float* __restrict__ bias, us* __restrict__ ydec, int vb)
{
  const int lane = threadIdx.x & 63, wv = threadIdx.x >> 6;
  const int l15 = lane & 15, l4 = lane >> 4;
  const int mbase = (vb >> 2) * 64 + wv * 16;
  const int nbase = (vb & 3) * 64;
  f4_t acc[4] = {};
  for (int k0 = 0; k0 < 256; k0 += 32) {
    bf8_t a = *(const bf8_t*)&A[(size_t)(mbase + l15) * 256 + k0 + 8 * l4];
#pragma unroll
    for (int nt = 0; nt < 4; ++nt) {
      bf8_t b = *(const bf8_t*)&Bw[(size_t)(nbase + nt * 16 + l15) * 256 + k0 + 8 * l4];
      acc[nt] = __builtin_amdgcn_mfma_f32_16x16x32_bf16(a, b, acc[nt], 0, 0, 0);
    }
  }
#pragma unroll
  for (int nt = 0; nt < 4; ++nt) {
    int col = nbase + nt * 16 + l15;
    float bv = bias[col];
#pragma unroll
    for (int r = 0; r < 4; ++r) {
      int row = mbase + l4 * 4 + r;
      int orow = (row & 31) * 16 + (row >> 5);   // b*16 + tt
      ydec[(size_t)orow * 256 + col] = f2bf(acc[nt][r] + bv);
    }
  }
}

// dl GEMM tile: rows rofs..rofs+511, dl-permuted bias, gelu, bf16
DEV void dlgemm_tile(const us* __restrict__ A, const us* __restrict__ Bw,
                     const float* __restrict__ bias, us* __restrict__ C,
                     int vb, int rofs)
{
  const int lane = threadIdx.x & 63, wv = threadIdx.x >> 6;
  const int l15 = lane & 15, l4 = lane >> 4;
  const int mbase = rofs + (vb >> 6) * 64 + wv * 16;
  const int nbase = (vb & 63) * 64;
  f4_t acc[4] = {};
  for (int k0 = 0; k0 < 256; k0 += 32) {
    bf8_t a = *(const bf8_t*)&A[(size_t)(mbase + l15) * 256 + k0 + 8 * l4];
#pragma unroll
    for (int nt = 0; nt < 4; ++nt) {
      bf8_t b = *(const bf8_t*)&Bw[(size_t)(nbase + nt * 16 + l15) * 256 + k0 + 8 * l4];
      acc[nt] = __builtin_amdgcn_mfma_f32_16x16x32_bf16(a, b, acc[nt], 0, 0, 0);
    }
  }
#pragma unroll
  for (int nt = 0; nt < 4; ++nt) {
    int col = nbase + nt * 16 + l15;
    float bv = bias[(col & 63) * 64 + (col >> 6)];
#pragma unroll
    for (int r = 0; r < 4; ++r) {
      int row = mbase + l4 * 4 + r;
      C[(size_t)row * 4096 + col] = f2bf(gelu_f(acc[nt][r] + bv));
    }
  }
}

// dt3 tile (device fn): PRED=1 -> n=nl, store fout, compare ref(=t);
// PRED=0 -> n=512+nl, compare ref(=x). partials[(PRED?0:2048)+vb].
template<int PRED>
DEV void dt3_tile(const us* __restrict__ in, const float* __restrict__ w,
                  const float* __restrict__ bias, const float* __restrict__ ref,
                  float* __restrict__ fout, float* __restrict__ partials,
                  int vb, float* sw, float* ws4)
{
  for (int i2 = threadIdx.x; i2 < 288; i2 += 256) sw[i2] = w[i2];
  __syncthreads();
  int idx = vb * 256 + threadIdx.x;
  int j = idx & 31, i = (idx >> 5) & 31, nl = idx >> 10;   // nl 0..511
  int n = PRED ? nl : (512 + nl);
  bool okj = (j < 31), oki = (i < 31);
  const us* r00 = in + (((size_t)n * 32 + i) * 32 + j) * 32;
  const us* r01 = r00 + 32;
  const us* r10 = r00 + 1024;
  const us* r11 = r10 + 32;
  float b0 = bias[0];
  float acc00 = b0, acc01 = b0, acc10 = b0, acc11 = b0;
  uint4 z4 = {0, 0, 0, 0};
#pragma unroll
  for (int g2 = 0; g2 < 4; ++g2) {
    uint4 v00 = *(const uint4*)&r00[g2 * 8];
    uint4 v01 = okj ? *(const uint4*)&r01[g2 * 8] : z4;
    uint4 v10 = oki ? *(const uint4*)&r10[g2 * 8] : z4;
    uint4 v11 = (oki && okj) ? *(const uint4*)&r11[g2 * 8] : z4;
    unsigned a00[4] = {v00.x, v00.y, v00.z, v00.w};
    unsigned a01[4] = {v01.x, v01.y, v01.z, v01.w};
    unsigned a10[4] = {v10.x, v10.y, v10.z, v10.w};
    unsigned a11[4] = {v11.x, v11.y, v11.z, v11.w};
#pragma unroll
    for (int h2 = 0; h2 < 4; ++h2) {
      int c0 = (g2 * 8 + h2 * 2) * 9;
      float xl, xh;
      xl = __uint_as_float(a00[h2] << 16); xh = __uint_as_float(a00[h2] & 0xffff0000u);
      acc00 = fmaf(xl, sw[c0 + 4], acc00); acc00 = fmaf(xh, sw[c0 + 13], acc00);
      acc01 = fmaf(xl, sw[c0 + 5], acc01); acc01 = fmaf(xh, sw[c0 + 14], acc01);
      acc10 = fmaf(xl, sw[c0 + 7], acc10); acc10 = fmaf(xh, sw[c0 + 16], acc10);
      acc11 = fmaf(xl, sw[c0 + 8], acc11); acc11 = fmaf(xh, sw[c0 + 17], acc11);
      xl = __uint_as_float(a01[h2] << 16); xh = __uint_as_float(a01[h2] & 0xffff0000u);
      acc01 = fmaf(xl, sw[c0 + 3], acc01); acc01 = fmaf(xh, sw[c0 + 12], acc01);
      acc11 = fmaf(xl, sw[c0 + 6], acc11); acc11 = fmaf(xh, sw[c0 + 15], acc11);
      xl = __uint_as_float(a10[h2] << 16); xh = __uint_as_float(a10[h2] & 0xffff0000u);
      acc10 = fmaf(xl, sw[c0 + 1], acc10); acc10 = fmaf(xh, sw[c0 + 10], acc10);
      acc11 = fmaf(xl, sw[c0 + 2], acc11); acc11 = fmaf(xh, sw[c0 + 11], acc11);
      xl = __uint_as_float(a11[h2] << 16); xh = __uint_as_float(a11[h2] & 0xffff0000u);
      acc11 = fmaf(xl, sw[c0 + 0], acc11); acc11 = fmaf(xh, sw[c0 + 9], acc11);
    }
  }
  float o00 = tanh_f(acc00), o01 = tanh_f(acc01);
  float o10 = tanh_f(acc10), o11 = tanh_f(acc11);
  size_t px = (size_t)(2 * i) * 64 + 2 * j;
  if (PRED) {
    float* fb = fout + (size_t)nl * 4096;
    fb[px] = o00;      fb[px + 1] = o01;
    fb[px + 64] = o10; fb[px + 65] = o11;
  }
  const float* rr = ref + (size_t)nl * 4096;
  float d0 = o00 - rr[px],      d1 = o01 - rr[px + 1];
  float d2 = o10 - rr[px + 64], d3 = o11 - rr[px + 65];
  float s = d0 * d0 + d1 * d1 + d2 * d2 + d3 * d3;
#pragma unroll
  for (int off = 32; off > 0; off >>= 1) s += __shfl_down(s, off);
  if ((threadIdx.x & 63) == 0) ws4[threadIdx.x >> 6] = s;
  __syncthreads();
  if (threadIdx.x == 0) partials[(PRED ? 0 : 2048) + vb] = ws4[0] + ws4[1] + ws4[2] + ws4[3];
  __syncthreads();
}

// ---------------------------------------------------------------------------
// MEGA kernel: blocks 0..159 = LSTM; 160..255 = rec-half decoder.
// ---------------------------------------------------------------------------
#define LSTM_NB 160

DEV void gridbar(unsigned* bar, unsigned target) {
  __syncthreads();
  if (threadIdx.x == 0) {
    __hip_atomic_fetch_add(bar, 1u, __ATOMIC_RELEASE, __HIP_MEMORY_SCOPE_AGENT);
    unsigned spins = 0;
    while (__hip_atomic_load(bar, __ATOMIC_RELAXED, __HIP_MEMORY_SCOPE_AGENT) < target) {
      __builtin_amdgcn_s_sleep(2);
      if (++spins > (1u << 24)) break;   // safety valve
    }
    (void)__hip_atomic_load(bar, __ATOMIC_ACQUIRE, __HIP_MEMORY_SCOPE_AGENT);
  }
  __syncthreads();
}

DEV void spin_min16s(unsigned* f, unsigned tgt) {
  if ((int)tgt <= 0) return;
  unsigned spins = 0;
  for (;;) {
    unsigned m = 0xffffffffu;
#pragma unroll
    for (int i = 0; i < 16; ++i) {
      unsigned v = __hip_atomic_load(f + i * 32, __ATOMIC_RELAXED, __HIP_MEMORY_SCOPE_AGENT);
      m = v < m ? v : m;
    }
    if (m >= tgt) return;
    if (++spins > (1u << 22)) return;    // safety valve
  }
}

__global__ __launch_bounds__(256, 1) void mega_k(
    const float* __restrict__ Wih,
    const float* __restrict__ Whh, const us* __restrict__ meffb,
    const float* __restrict__ bih, const float* __restrict__ bhh,
    const float* __restrict__ beff,
    const us* __restrict__ zbf, us* __restrict__ hbf, us* __restrict__ h9sav,
    unsigned* __restrict__ bar,
    const us* __restrict__ ydec, const us* __restrict__ dlWb,
    const float* __restrict__ dl_b,
    const us* __restrict__ wbp_dt1, const float* __restrict__ dt1_b,
    const us* __restrict__ wb_dc1,  const float* __restrict__ dc1_b,
    const us* __restrict__ wbp_dt2, const float* __restrict__ dt2_b,
    const us* __restrict__ wb_dc2,  const float* __restrict__ dc2_b,
    const float* __restrict__ dt3_w, const float* __restrict__ dt3_b,
    const float* __restrict__ xref,
    us* __restrict__ bufA, us* __restrict__ bufB,
    float* __restrict__ partials)
{
  __shared__ __align__(16) unsigned char smem[109568];

  const int tid = threadIdx.x;
  const int bid = blockIdx.x;

  if (bid < 160) {
    // ================= LSTM path =========================================
    us*    s_w   = (us*)smem;                      // 65536 B
    us*    s_x   = (us*)(smem + 65536);            // 16384 B
    us*    s_h   = (us*)(smem + 81920);            // 16384 B
    float* zsm   = (float*)(smem + 98304);         // 8704 B
    float* cls   = (float*)(smem + 107008);        // 2048 B
    float* sbias = (float*)(smem + 109056);        // 256 B
    float* sb2   = (float*)(smem + 109312);        // 256 B

    const int l   = bid >> 4;
    const int jg  = bid & 15;
    const int col0 = jg * 16;
    const int lane = tid & 63, g = tid >> 6;
    const int l15 = lane & 15, l4 = lane >> 4;
    const int gtid = bid * 256 + tid;

    unsigned* fl = bar + 64;
    unsigned* fown = fl + (size_t)l * 16 * 32;

    for (int i = gtid; i < 81920; i += LSTM_NB * 256) hbf[81920 + i] = 0;
    // stage weights: direct fp32 -> bf16 frag conversion from Wih/Whh
    for (int c = tid; c < 4096; c += 256) {
      int gm = c >> 9;                 // g*2 + m
      int gg = gm >> 1, m = gm & 1;
      int c2 = c & 511;
      int ks = c2 >> 6, ln = c2 & 63;
      const float* src = (m == 0 ? Wih : Whh)
          + ((size_t)l * 1024 + gg * 256 + jg * 16 + (ln & 15)) * 256
          + ks * 32 + (ln >> 4) * 8;
      us tmp[8];
#pragma unroll
      for (int e = 0; e < 8; ++e) tmp[e] = f2bf(src[e]);
      *(int4*)&s_w[(size_t)c * 8] = *(int4*)tmp;
    }
    for (int i = tid; i < 512; i += 256) cls[i] = 0.f;
    if (tid < 64) {
      int gg = tid >> 4, j = tid & 15;
      sbias[tid] = bih[l * 1024 + gg * 256 + col0 + j]
                 + bhh[l * 1024 + gg * 256 + col0 + j];
      sb2[tid]   = beff[gg * 256 + col0 + j] + bhh[gg * 256 + col0 + j];
    }

    gridbar(bar, LSTM_NB);

    for (int t = 0; t <= 30; ++t) {
      const int cur = t & 1, prv = cur ^ 1;
      const bool p2 = (t >= 16);
      const bool p2l0 = p2 && (l == 0);

      if (tid == 0) {
        spin_min16s(fown, (unsigned)t);
        (void)__hip_atomic_load(fown, __ATOMIC_ACQUIRE, __HIP_MEMORY_SCOPE_AGENT);
      }
      __syncthreads();
      const us* hb = hbf + (size_t)((prv * 10 + l) * 32) * 256;
#pragma unroll
      for (int i = 0; i < 4; ++i) {
        int c = tid + i * 256;
        int sw = (c & ~31) | ((c & 31) ^ ((c >> 5) & 7));
        *(int4*)&s_h[(size_t)sw * 8] = *(const int4*)&hb[(size_t)c * 8];
      }
      if (tid == 0) {
        if (l == 0) {
          if (t >= 16) spin_min16s(fl + (size_t)9 * 16 * 32, (unsigned)t);
        } else {
          spin_min16s(fl + (size_t)(l - 1) * 16 * 32, (unsigned)(t + 1));
        }
        if (t >= 2) {
          if (l < 9) spin_min16s(fl + (size_t)(l + 1) * 16 * 32, (unsigned)(t - 1));
          else if (t >= 17) spin_min16s(fl, (unsigned)t);
        }
        (void)__hip_atomic_load(fown, __ATOMIC_ACQUIRE, __HIP_MEMORY_SCOPE_AGENT);
      }
      __syncthreads();
      const us* xb =
          (l == 0) ? (p2 ? (hbf + (size_t)((prv * 10 + 9) * 32) * 256)
                         : (zbf + (size_t)t * 32 * 256))
                   : (hbf + (size_t)((cur * 10 + l - 1) * 32) * 256);
#pragma unroll
      for (int i = 0; i < 4; ++i) {
        int c = tid + i * 256;
        int sw = (c & ~31) | ((c & 31) ^ ((c >> 5) & 7));
        *(int4*)&s_x[(size_t)sw * 8] = *(const int4*)&xb[(size_t)c * 8];
      }
      __syncthreads();
      f4_t a0 = {}, a1 = {}, b0 = {}, b1 = {};
#pragma unroll
      for (int ks = 0; ks < 8; ++ks) {
        bf8_t bwi = *(const bf8_t*)&s_w[(size_t)((g * 2 + 0) * 4096 + ks * 512 + lane * 8)];
        bf8_t bwh = *(const bf8_t*)&s_w[(size_t)((g * 2 + 1) * 4096 + ks * 512 + lane * 8)];
        int cx0 = (l15 << 5) | ((ks * 4 + l4) ^ (l15 & 7));
        int cx1 = ((16 + l15) << 5) | ((ks * 4 + l4) ^ (l15 & 7));
        bf8_t ax0 = *(const bf8_t*)&s_x[(size_t)cx0 * 8];
        bf8_t ax1 = *(const bf8_t*)&s_x[(size_t)cx1 * 8];
        bf8_t ah0 = *(const bf8_t*)&s_h[(size_t)cx0 * 8];
        bf8_t ah1 = *(const bf8_t*)&s_h[(size_t)cx1 * 8];
        a0 = __builtin_amdgcn_mfma_f32_16x16x32_bf16(ax0, bwi, a0, 0, 0, 0);
        a1 = __builtin_amdgcn_mfma_f32_16x16x32_bf16(ax1, bwi, a1, 0, 0, 0);
        b0 = __builtin_amdgcn_mfma_f32_16x16x32_bf16(ah0, bwh, b0, 0, 0, 0);
        b1 = __builtin_amdgcn_mfma_f32_16x16x32_bf16(ah1, bwh, b1, 0, 0, 0);
      }
#pragma unroll
      for (int r = 0; r < 4; ++r) {
        zsm[(g * 32 + l4 * 4 + r) * 17 + l15] = a0[r] + b0[r];
        zsm[(g * 32 + 16 + l4 * 4 + r) * 17 + l15] = a1[r] + b1[r];
      }
      __syncthreads();
#pragma unroll
      for (int half = 0; half < 2; ++half) {
        int e = tid + half * 256;
        int b = e >> 4, j = e & 15;
        float zi = zsm[(0 * 32 + b) * 17 + j] + (p2l0 ? sb2[j]      : sbias[j]);
        float zf = zsm[(1 * 32 + b) * 17 + j] + (p2l0 ? sb2[16 + j] : sbias[16 + j]);
        float zg = zsm[(2 * 32 + b) * 17 + j] + (p2l0 ? sb2[32 + j] : sbias[32 + j]);
        float zo = zsm[(3 * 32 + b) * 17 + j] + (p2l0 ? sb2[48 + j] : sbias[48 + j]);
        float cold = cls[b * 16 + j];
        float cn = sigm_f(zf) * cold + sigm_f(zi) * tanh_f(zg);
        cls[b * 16 + j] = cn;
        float hn = sigm_f(zo) * tanh_f(cn);
        float hn_hi = __shfl_down(hn, 1);
        if (!(j & 1)) {
          unsigned pk = (unsigned)f2bf(hn) | ((unsigned)f2bf(hn_hi) << 16);
          astore((unsigned*)&hbf[(size_t)((cur * 10 + l) * 32 + b) * 256 + col0 + j], pk);
          if (l == 9 && t >= 15)
            astore((unsigned*)&h9sav[(size_t)((t - 15) * 32 + b) * 256 + col0 + j], pk);
        }
      }
      __syncthreads();
      if (tid == 0)
        __hip_atomic_store(&fown[jg * 32], (unsigned)(t + 1),
                           __ATOMIC_RELEASE, __HIP_MEMORY_SCOPE_AGENT);
      if (l == 0 && t == 15) {
        for (int c = tid; c < 2048; c += 256) {
          int gg = c >> 9, c2 = c & 511;
          const us* src = meffb + ((size_t)(gg * 16 + jg) * 8) * 512;
          *(int4*)&s_w[(size_t)((gg * 2) * 512 + c2) * 8] = *(const int4*)&src[(size_t)c2 * 8];
        }
        __syncthreads();
      }
    }
  } else {
    // ================= rec-half decoder path (96 blocks) ==================
    us* lds = (us*)smem;
    float* swq = (float*)(smem + 49152);
    float* ws4 = (float*)(smem + 50432);
    unsigned* bar96 = bar + 32;
    const int wg = bid - 160;
    int ep2 = 0;

    for (int vb = wg; vb < 512; vb += 96)
      dlgemm_tile(ydec, dlWb, dl_b, bufB, vb, 512);
    ++ep2; gridbar(bar96, (unsigned)(ep2 * 96));
    for (int vb = wg; vb < 512; vb += 96)
      tconvp_tile<64, 64, 8, 8, 8, 8>(bufB, wbp_dt1, dt1_b, bufA, vb, 512, lds);
    ++ep2; gridbar(bar96, (unsigned)(ep2 * 96));
    for (int vb = wg; vb < 512; vb += 96)
      convmf_tile<64, 64, 16, 16, 16, 16, 0>(bufA, wb_dc1, dc1_b, bufB, vb, 512, lds);
    ++ep2; gridbar(bar96, (unsigned)(ep2 * 96));
    for (int vb = wg; vb < 1024; vb += 96)
      tconvp_tile<64, 32, 16, 16, 8, 16>(bufB, wbp_dt2, dt2_b, bufA, vb, 512, lds);
    ++ep2; gridbar(bar96, (unsigned)(ep2 * 96));
    for (int vb = wg; vb < 2048; vb += 96)
      convmf_tile<32, 32, 32, 32, 16, 16, 0>(bufA, wb_dc2, dc2_b, bufB, vb, 512, lds);
    ++ep2; gridbar(bar96, (unsigned)(ep2 * 96));
    for (int vb = wg; vb < 2048; vb += 96)
      dt3_tile<0>(bufB, dt3_w, dt3_b, xref, (float*)0, partials, vb, swq, ws4);
  }
}

// ---------------------------------------------------------------------------
// PRED mega: fused pred decoder + loss. Grid 768 (3 blocks/CU, co-resident),
// 44KB LDS carve, spread-flag epoch barrier (no atomics).
// ---------------------------------------------------------------------------
DEV void predbar(unsigned* pf, unsigned ep) {
  __syncthreads();
  if (threadIdx.x == 0)
    __hip_atomic_store(&pf[(size_t)blockIdx.x * 32], ep,
                       __ATOMIC_RELEASE, __HIP_MEMORY_SCOPE_AGENT);
  unsigned spins = 0;
  for (int s = threadIdx.x; s < 768; s += 256) {
    while (__hip_atomic_load(&pf[(size_t)s * 32],
                             __ATOMIC_RELAXED, __HIP_MEMORY_SCOPE_AGENT) < ep) {
      if (++spins > (1u << 25)) break;   // safety valve
    }
  }
  (void)__hip_atomic_load(&pf[(size_t)threadIdx.x * 32],
                          __ATOMIC_ACQUIRE, __HIP_MEMORY_SCOPE_AGENT);
  __syncthreads();
}

__global__ __launch_bounds__(256, 3) void predm_k(
    const us* __restrict__ h9sav, const us* __restrict__ lwbp,
    const float* __restrict__ lb,  us* __restrict__ ydec,
    const us* __restrict__ dlWb,   const float* __restrict__ dl_b,
    const us* __restrict__ wbp_dt1, const float* __restrict__ dt1_b,
    const us* __restrict__ wb_dc1,  const float* __restrict__ dc1_b,
    const us* __restrict__ wbp_dt2, const float* __restrict__ dt2_b,
    const us* __restrict__ wb_dc2,  const float* __restrict__ dc2_b,
    const float* __restrict__ dt3_w, const float* __restrict__ dt3_b,
    const float* __restrict__ tref,
    us* __restrict__ bufA, us* __restrict__ bufB,
    float* __restrict__ fout, float* __restrict__ partials,
    float* __restrict__ out01, unsigned* __restrict__ pf)
{
  __shared__ __align__(16) unsigned char smem[45056];
  us* lds = (us*)smem;                      // <= 43776 B per stage
  float* swq = (float*)(smem + 43776);      // 1152 B
  float* ws4 = (float*)(smem + 44928);      // 16 B
  const int bid = blockIdx.x;
  unsigned ep = 0;

  // P0: outs-GEMM -> ydec pred rows (32 tiles)
  for (int vb = bid; vb < 32; vb += 768)
    outsgemm_tile(h9sav, lwbp, lb, ydec, vb);
  ++ep; predbar(pf, ep);
  // P1: dl pred GEMM (512 tiles) -> bufB rows 0..511
  for (int vb = bid; vb < 512; vb += 768)
    dlgemm_tile(ydec, dlWb, dl_b, bufB, vb, 0);
  ++ep; predbar(pf, ep);
  // P2: dt1 (512)
  for (int vb = bid; vb < 512; vb += 768)
    tconvp_tile<64, 64, 8, 8, 8, 8>(bufB, wbp_dt1, dt1_b, bufA, vb, 0, lds);
  ++ep; predbar(pf, ep);
  // P3: dc1 (512)
  for (int vb = bid; vb < 512; vb += 768)
    convmf_tile<64, 64, 16, 16, 16, 16, 0>(bufA, wb_dc1, dc1_b, bufB, vb, 0, lds);
  ++ep; predbar(pf, ep);
  // P4: dt2 (1024)
  for (int vb = bid; vb < 1024; vb += 768)
    tconvp_tile<64, 32, 16, 16, 8, 16>(bufB, wbp_dt2, dt2_b, bufA, vb, 0, lds);
  ++ep; predbar(pf, ep);
  // P5: dc2 (2048)
  for (int vb = bid; vb < 2048; vb += 768)
    convmf_tile<32, 32, 32, 32, 16, 16, 0>(bufA, wb_dc2, dc2_b, bufB, vb, 0, lds);
  ++ep; predbar(pf, ep);
  // P6: dt3 pred + partials (2048)
  for (int vb = bid; vb < 2048; vb += 768)
    dt3_tile<1>(bufB, dt3_w, dt3_b, tref, fout, partials, vb, swq, ws4);
  ++ep; predbar(pf, ep);
  // P7: loss reduce (blocks 0,1); partials rec half written by mega.
  if (bid < 2) {
    float* red = (float*)smem;
    int base = bid * 2048;
    float s = 0.f;
    for (int i = threadIdx.x; i < 2048; i += 256) s += partials[base + i];
    red[threadIdx.x] = s;
    __syncthreads();
#pragma unroll
    for (int st = 128; st > 0; st >>= 1) {
      if (threadIdx.x < st) red[threadIdx.x] += red[threadIdx.x + st];
      __syncthreads();
    }
    if (threadIdx.x == 0) out01[bid] = red[0] * (1.0f / 2097152.0f);
  }
}

// ---------------------------------------------------------------------------
extern "C" void kernel_launch(void* const* d_in, const int* in_sizes, int n_in,
                              void* d_out, int out_size, void* d_ws, size_t ws_size,
                              hipStream_t stream) {
  const float* x     = (const float*)d_in[0];
  const float* t     = (const float*)d_in[1];
  const float* ec1_w = (const float*)d_in[2];
  const float* ec1_b = (const float*)d_in[3];
  const float* ec2_w = (const float*)d_in[4];
  const float* ec2_b = (const float*)d_in[5];
  const float* ec3_w = (const float*)d_in[6];
  const float* ec3_b = (const float*)d_in[7];
  const float* ec4_w = (const float*)d_in[8];
  const float* ec4_b = (const float*)d_in[9];
  const float* ec5_w = (const float*)d_in[10];
  const float* ec5_b = (const float*)d_in[11];
  const float* el_w  = (const float*)d_in[12];
  const float* el_b  = (const float*)d_in[13];
  const float* dl_w  = (const float*)d_in[14];
  const float* dl_b  = (const float*)d_in[15];
  const float* dt1_w = (const float*)d_in[16];
  const float* dt1_b = (const float*)d_in[17];
  const float* dc1_w = (const float*)d_in[18];
  const float* dc1_b = (const float*)d_in[19];
  const float* dt2_w = (const float*)d_in[20];
  const float* dt2_b = (const float*)d_in[21];
  const float* dc2_w = (const float*)d_in[22];
  const float* dc2_b = (const float*)d_in[23];
  const float* dt3_w = (const float*)d_in[24];
  const float* dt3_b = (const float*)d_in[25];
  const float* Wih   = (const float*)d_in[26];
  const float* Whh   = (const float*)d_in[27];
  const float* bih   = (const float*)d_in[28];
  const float* bhh   = (const float*)d_in[29];
  const float* lw    = (const float*)d_in[30];
  const float* lb    = (const float*)d_in[31];
  float* out = (float*)d_out;

  char* base = (char*)d_ws;
  size_t off = 0;
  auto alloc = [&](size_t bytes) -> char* {
    char* p = base + off;
    off += (bytes + 255) & ~(size_t)255;
    return p;
  };
  unsigned* bar   = (unsigned*)alloc(163840);   // mega flags + predm flags (@+32KB)
  float* zpart    = (float*)alloc((size_t)8 * 512 * 256 * 4);
  us*    zbf      = (us*)alloc((size_t)16 * 32 * 256 * 2);
  us*    hbf      = (us*)alloc((size_t)2 * 10 * 32 * 256 * 2);
  us*    h9sav    = (us*)alloc((size_t)16 * 32 * 256 * 2);
  us*    ydec     = (us*)alloc((size_t)1024 * 256 * 2);
  float* partials = (float*)alloc((size_t)16384 * 4);
  us* wb_ec2 = (us*)alloc((size_t)32 * 288 * 2);
  us* wb_ec3 = (us*)alloc((size_t)64 * 288 * 2);
  us* wb_ec4 = (us*)alloc((size_t)64 * 576 * 2);
  us* wb_ec5 = (us*)alloc((size_t)64 * 576 * 2);
  us* wbp_dt1 = (us*)alloc((size_t)64 * 576 * 2);
  us* wb_dc1 = (us*)alloc((size_t)64 * 576 * 2);
  us* wbp_dt2 = (us*)alloc((size_t)32 * 576 * 2);
  us* wb_dc2 = (us*)alloc((size_t)32 * 288 * 2);
  us* elWb   = (us*)alloc((size_t)256 * 4096 * 2);
  us* dlWb   = (us*)alloc((size_t)4096 * 256 * 2);
  us* wih0b  = (us*)alloc((size_t)1024 * 256 * 2);
  us* lwTb   = (us*)alloc((size_t)256 * 256 * 2);
  us* lwbp   = (us*)alloc((size_t)256 * 256 * 2);
  us* meffb  = (us*)alloc((size_t)1024 * 256 * 2);
  float* beff = (float*)alloc((size_t)1024 * 4);
  us* enc5   = (us*)alloc((size_t)512 * 4096 * 2);
  us* bufA   = (us*)alloc((size_t)1024 * 32 * 32 * 32 * 2);
  us* bufB   = (us*)alloc((size_t)1024 * 32 * 32 * 32 * 2);
  (void)in_sizes; (void)n_in; (void)out_size; (void)ws_size;

  hipMemsetAsync(bar, 0, 163840, stream);
  unsigned* pf = bar + 8192;   // predm flags region (byte offset 32768)

  // ---- weight prep (fused) + meff direct frag write ----
  prep_all_k<<<10524, 256, 0, stream>>>(ec2_w, ec3_w, ec4_w, ec5_w,
                                        dt1_w, dc1_w, dt2_w, dc2_w,
                                        wb_ec2, wb_ec3, wb_ec4, wb_ec5,
                                        wbp_dt1, wb_dc1, wbp_dt2, wb_dc2,
                                        Wih, lw, lb, bih, wih0b, lwTb, lwbp, beff,
                                        el_w, dl_w, elWb, dlWb);
  gemm16_k<2, false, 3><<<dim3(4, 16), 256, 0, stream>>>(wih0b, lwTb, lb, meffb, 1024, 256, 256);

  // ---- encoder: x frames only (512 images) ----
  ec1_k<<<2048, 256, 0, stream>>>(x, ec1_w, ec1_b, bufA);
  convmf_k<32, 32, 32, 32, 16, 16, 0><<<2048, 256, 0, stream>>>(bufA, wb_ec2, ec2_b, bufB);
  convmf_k<32, 64, 32, 32, 16, 16, 1><<<512, 256, 0, stream>>>(bufB, wb_ec3, ec3_b, bufA);
  convmf_k<64, 64, 16, 16, 16, 16, 0><<<512, 256, 0, stream>>>(bufA, wb_ec4, ec4_b, bufB);
  convmf_k<64, 64, 16, 16, 8, 8, 1><<<512, 256, 0, stream>>>(bufB, wb_ec5, ec5_b, enc5);
  elgemm_splitk_k<<<dim3(4, 8, 8), 256, 0, stream>>>(enc5, elWb, zpart);
  zcombine_k<<<512, 256, 0, stream>>>(zpart, el_b, zbf, ydec);

  // ---- MEGA: LSTM (160 blocks) || rec-half decoder (96 blocks) ----
  mega_k<<<256, 256, 0, stream>>>(Wih, Whh, meffb, bih, bhh, beff,
                                  zbf, hbf, h9sav, bar,
                                  ydec, dlWb, dl_b,
                                  wbp_dt1, dt1_b, wb_dc1, dc1_b,
                                  wbp_dt2, dt2_b, wb_dc2, dc2_b,
                                  dt3_w, dt3_b, x, bufA, bufB, partials);

  // ---- PRED mega: fused pred decoder + loss (768 blocks, 3/CU) ----
  predm_k<<<768, 256, 0, stream>>>(h9sav, lwbp, lb, ydec, dlWb, dl_b,
                                   wbp_dt1, dt1_b, wb_dc1, dc1_b,
                                   wbp_dt2, dt2_b, wb_dc2, dc2_b,
                                   dt3_w, dt3_b, t,
                                   bufA, bufB, out + 2, partials, out, pf);
}

// Round 23
// 1031.011 us; speedup vs baseline: 1.5662x; 1.5662x over previous
//
#include <hip/hip_runtime.h>
#include <math.h>

#define DEV __device__ __forceinline__

typedef __attribute__((ext_vector_type(8))) short bf8_t;   // 8 x bf16 (4 VGPR)
typedef __attribute__((ext_vector_type(4))) float f4_t;    // MFMA acc
typedef unsigned short us;

DEV float sigm_f(float v) { return 1.0f / (1.0f + __expf(-v)); }
DEV float tanh_f(float v) { return fmaf(-2.0f, 1.0f / (1.0f + __expf(2.0f * v)), 1.0f); }
DEV float gelu_f(float v) {
  float u = 0.79788456080f * fmaf(0.044715f * v * v, v, v);
  return 0.5f * v * (1.0f + tanh_f(u));
}
DEV unsigned short f2bf(float f) {            // RNE float->bf16
  unsigned u = __float_as_uint(f);
  u = (u + 0x7FFFu + ((u >> 16) & 1u)) >> 16;
  return (unsigned short)u;
}
DEV void astore(unsigned* p, unsigned v) {
  __hip_atomic_store(p, v, __ATOMIC_RELAXED, __HIP_MEMORY_SCOPE_AGENT);
}

// ---------------------------------------------------------------------------
// Fused weight prep: conv weights + misc + el/dl. One launch.
// ---------------------------------------------------------------------------
DEV void prep_norm(int li, const float* w, us* wb, int CIN) {
  int ci = li % CIN;
  int r  = li / CIN;
  int kw = r % 3; r /= 3;
  int kh = r % 3;
  int co = r / 3;
  wb[li] = f2bf(w[((co * CIN + ci) * 3 + kh) * 3 + kw]);
}
DEV void prep_par(int li, const float* w, us* wb, int COUT, int CIN) {
  const int TAPORD[9] = {4, 3, 5, 1, 7, 0, 2, 6, 8};
  int ci = li % CIN;
  int r  = li / CIN;
  int ti = r % 9;
  int co = r / 9;
  int tap = TAPORD[ti];
  int kh = tap / 3, kw = tap % 3;
  wb[li] = f2bf(w[((ci * COUT + co) * 3 + (2 - kh)) * 3 + (2 - kw)]);
}

__global__ __launch_bounds__(256) void prep_all_k(
    const float* __restrict__ ec2, const float* __restrict__ ec3,
    const float* __restrict__ ec4, const float* __restrict__ ec5,
    const float* __restrict__ dt1, const float* __restrict__ dc1,
    const float* __restrict__ dt2, const float* __restrict__ dc2,
    us* __restrict__ o_ec2, us* __restrict__ o_ec3,
    us* __restrict__ o_ec4, us* __restrict__ o_ec5,
    us* __restrict__ o_dt1, us* __restrict__ o_dc1,
    us* __restrict__ o_dt2, us* __restrict__ o_dc2,
    const float* __restrict__ Wih, const float* __restrict__ lw,
    const float* __restrict__ lb,  const float* __restrict__ bih,
    us* __restrict__ wih0b, us* __restrict__ lwTb,
    us* __restrict__ lwbp,  float* __restrict__ beff,
    const float* __restrict__ el_w, const float* __restrict__ dl_w,
    us* __restrict__ elWb, us* __restrict__ dlWb)
{
  int idx = blockIdx.x * 256 + threadIdx.x;            // < 2694144
  if (idx < 202752) {
    if (idx < 9216)        prep_norm(idx,          ec2, o_ec2, 32);
    else if (idx < 27648)  prep_norm(idx - 9216,   ec3, o_ec3, 32);
    else if (idx < 64512)  prep_norm(idx - 27648,  ec4, o_ec4, 64);
    else if (idx < 101376) prep_norm(idx - 64512,  ec5, o_ec5, 64);
    else if (idx < 138240) prep_par (idx - 101376, dt1, o_dt1, 64, 64);
    else if (idx < 175104) prep_norm(idx - 138240, dc1, o_dc1, 64);
    else if (idx < 193536) prep_par (idx - 175104, dt2, o_dt2, 32, 64);
    else                   prep_norm(idx - 193536, dc2, o_dc2, 32);
  } else if (idx < 596992) {
    int i2 = idx - 202752;
    if (i2 < 262144) {
      wih0b[i2] = f2bf(Wih[i2]);
    } else if (i2 < 327680) {
      int i = i2 - 262144;
      int n = i & 255, kcol = i >> 8;
      lwTb[i] = f2bf(lw[(size_t)n * 256 + kcol]);
    } else if (i2 < 393216) {
      int i = i2 - 327680;
      lwbp[i] = f2bf(lw[i]);
    } else if (i2 < 394240) {
      int j = i2 - 393216;
      float s = bih[j];
      const float* row = Wih + (size_t)j * 256;
      for (int n = 0; n < 256; ++n) s = fmaf(row[n], lb[n], s);
      beff[j] = s;
    }
  } else {
    int i3 = idx - 596992;
    if (i3 < 1048576) {
      int kn = i3 & 4095, n = i3 >> 12;
      elWb[i3] = f2bf(el_w[(size_t)n * 4096 + ((kn & 63) * 64 + (kn >> 6))]);
    } else {
      int i = i3 - 1048576;
      int k = i & 255, nout = i >> 8;
      dlWb[i] = f2bf(dl_w[(size_t)((nout & 63) * 64 + (nout >> 6)) * 256 + k]);
    }
  }
}

// ---------------------------------------------------------------------------
// ec1: x frames ONLY (512 images)
// ---------------------------------------------------------------------------
__global__ __launch_bounds__(256) void ec1_k(
    const float* __restrict__ x,
    const float* __restrict__ w, const float* __restrict__ bias,
    us* __restrict__ out)
{
  __shared__ float sw[288];
  __shared__ float sb[32];
  for (int i = threadIdx.x; i < 288; i += 256) sw[i] = w[i];
  if (threadIdx.x < 32) sb[threadIdx.x] = bias[threadIdx.x];
  __syncthreads();
  int idx = blockIdx.x * 256 + threadIdx.x;     // < 512*32*32
  int ox = idx & 31, oy = (idx >> 5) & 31, n = idx >> 10;   // n 0..511
  const float* ip = x + (size_t)n * 4096;
  float pv[9];
#pragma unroll
  for (int kh = 0; kh < 3; ++kh) {
    int iy = oy * 2 + kh - 1;
#pragma unroll
    for (int kw = 0; kw < 3; ++kw) {
      int ix = ox * 2 + kw - 1;
      pv[kh * 3 + kw] = ((unsigned)iy < 64u && (unsigned)ix < 64u) ? ip[iy * 64 + ix] : 0.f;
    }
  }
  us u[32];
#pragma unroll
  for (int co = 0; co < 32; ++co) {
    float a = sb[co];
#pragma unroll
    for (int i = 0; i < 9; ++i) a = fmaf(pv[i], sw[co * 9 + i], a);
    u[co] = f2bf(gelu_f(a));
  }
  us* op = out + (size_t)idx * 32;
#pragma unroll
  for (int p = 0; p < 4; ++p) {
    uint4 v;
    v.x = u[p*8+0] | (u[p*8+1] << 16);
    v.y = u[p*8+2] | (u[p*8+3] << 16);
    v.z = u[p*8+4] | (u[p*8+5] << 16);
    v.w = u[p*8+6] | (u[p*8+7] << 16);
    *(uint4*)&op[p * 8] = v;
  }
}

// ---------------------------------------------------------------------------
// Conv tile device fn (odd LDS stride). Trailing __syncthreads.
// ---------------------------------------------------------------------------
template<int CIN, int COUT, int HIN, int WIN, int TH, int TW, int MODE>
DEV void convmf_tile(const us* __restrict__ in, const us* __restrict__ wb,
                     const float* __restrict__ bias, us* __restrict__ out,
                     int vb, int nofs, us* lds)
{
  constexpr int HO  = (MODE == 1) ? HIN / 2 : HIN;
  constexpr int WO  = (MODE == 1) ? WIN / 2 : WIN;
  constexpr int TIH = (MODE == 1) ? 2 * TH + 1 : TH + 2;
  constexpr int TIW = (MODE == 1) ? 2 * TW + 1 : TW + 2;
  constexpr int TIWP = (TIW & 1) ? TIW : TIW + 1;
  constexpr int CG  = CIN / 8;
  constexpr int K   = 9 * CIN;
  constexpr int KS  = K / 32;
  constexpr int NT  = COUT / 16;
  constexpr int MT  = (TH * TW) / 16;
  constexpr int MPW = MT / 4;
  constexpr int TY  = HO / TH, TX = WO / TW;

  const int n = nofs + vb / (TY * TX);
  const int trem = vb % (TY * TX);
  const int ty0 = (trem / TX) * TH, tx0 = (trem % TX) * TW;

  constexpr int ENT = TIH * TIW * CG;
  for (int e = threadIdx.x; e < ENT; e += 256) {
    int txx = e % TIW;
    int rr  = e / TIW;
    int cg  = rr % CG;
    int tyy = rr / CG;
    int iy, ix; bool ok;
    if (MODE == 0) {
      iy = ty0 + tyy - 1; ix = tx0 + txx - 1;
      ok = (unsigned)iy < (unsigned)HIN && (unsigned)ix < (unsigned)WIN;
    } else {
      iy = 2 * ty0 + tyy - 1; ix = 2 * tx0 + txx - 1;
      ok = (unsigned)iy < (unsigned)HIN && (unsigned)ix < (unsigned)WIN;
    }
    int4 val = {0, 0, 0, 0};
    if (ok) val = *(const int4*)&in[(((size_t)n * HIN + iy) * WIN + ix) * CIN + cg * 8];
    *(int4*)&lds[(size_t)((tyy * CG + cg) * TIWP + txx) * 8] = val;
  }
  __syncthreads();

  const int lane = threadIdx.x & 63, wv = threadIdx.x >> 6;
  const int l15 = lane & 15, l4 = lane >> 4;

  f4_t acc[MPW][NT] = {};
  for (int ks = 0; ks < KS; ++ks) {
    const int tap = (ks * 32) / CIN;
    const int kh = tap / 3, kw = tap % 3;
    const int cb = ((ks * 32) % CIN) / 8 + l4;
    bf8_t bf[NT];
#pragma unroll
    for (int nt = 0; nt < NT; ++nt)
      bf[nt] = *(const bf8_t*)&wb[(size_t)(nt * 16 + l15) * K + ks * 32 + 8 * l4];
#pragma unroll
    for (int mi = 0; mi < MPW; ++mi) {
      int m = (wv * MPW + mi) * 16 + l15;
      int oy = m / TW, ox = m % TW;
      int rt = ((MODE == 1) ? 2 * oy : oy) + kh;
      int ct = ((MODE == 1) ? 2 * ox : ox) + kw;
      bf8_t a = *(const bf8_t*)&lds[(size_t)((rt * CG + cb) * TIWP + ct) * 8];
#pragma unroll
      for (int nt = 0; nt < NT; ++nt)
        acc[mi][nt] = __builtin_amdgcn_mfma_f32_16x16x32_bf16(a, bf[nt], acc[mi][nt], 0, 0, 0);
    }
  }

#pragma unroll
  for (int mi = 0; mi < MPW; ++mi) {
    int mbase = (wv * MPW + mi) * 16;
#pragma unroll
    for (int nt = 0; nt < NT; ++nt) {
      int co = nt * 16 + l15;
      float bv = bias[co];
#pragma unroll
      for (int r = 0; r < 4; ++r) {
        int m = mbase + l4 * 4 + r;
        int oy = m / TW, ox = m % TW;
        float v = acc[mi][nt][r] + bv;
        out[(((size_t)n * HO + ty0 + oy) * WO + (tx0 + ox)) * COUT + co] = f2bf(gelu_f(v));
      }
    }
  }
  __syncthreads();
}

// wrapper kernels (pred half + encoder, standalone)
template<int CIN, int COUT, int HIN, int WIN, int TH, int TW, int MODE>
__global__ __launch_bounds__(256) void convmf_k(
    const us* __restrict__ in, const us* __restrict__ wb,
    const float* __restrict__ bias, us* __restrict__ out)
{
  constexpr int TIH = (MODE == 1) ? 2 * TH + 1 : TH + 2;
  constexpr int TIW = (MODE == 1) ? 2 * TW + 1 : TW + 2;
  constexpr int TIWP = (TIW & 1) ? TIW : TIW + 1;
  __shared__ us lds[TIH * TIWP * (CIN / 8) * 8];
  convmf_tile<CIN, COUT, HIN, WIN, TH, TW, MODE>(in, wb, bias, out, blockIdx.x, 0, lds);
}

// ---------------------------------------------------------------------------
// tconv tile device fn (parity waves). Trailing __syncthreads.
// ---------------------------------------------------------------------------
template<int CIN, int COUT, int HIN, int WIN, int SH, int SW>
DEV void tconvp_tile(const us* __restrict__ in, const us* __restrict__ wbp,
                     const float* __restrict__ bias, us* __restrict__ out,
                     int vb, int nofs, us* lds)
{
  constexpr int HO = 2 * HIN, WO = 2 * WIN;
  constexpr int CG = CIN / 8;
  constexpr int TIH = SH + 1, TIW = SW + 1;
  constexpr int NT = COUT / 16;
  constexpr int MPW_P = (SH * SW) / 16;
  constexpr int TY = HIN / SH, TX = WIN / SW;

  const int n = nofs + vb / (TY * TX);
  const int trem = vb % (TY * TX);
  const int toy = trem / TX, tox = trem % TX;
  const int ty0s = toy * SH, tx0s = tox * SW;

  constexpr int ENT = TIH * TIW * CG;
  for (int e = threadIdx.x; e < ENT; e += 256) {
    int txx = e % TIW;
    int rr  = e / TIW;
    int cg  = rr % CG;
    int tyy = rr / CG;
    int iy = ty0s + tyy, ix = tx0s + txx;
    int4 val = {0, 0, 0, 0};
    if (iy < HIN && ix < WIN)
      val = *(const int4*)&in[(((size_t)n * HIN + iy) * WIN + ix) * CIN + cg * 8];
    *(int4*)&lds[(size_t)((tyy * CG + cg) * TIW + txx) * 8] = val;
  }
  __syncthreads();

  const int lane = threadIdx.x & 63, wv = threadIdx.x >> 6;
  const int l15 = lane & 15, l4 = lane >> 4;
  const int dy = wv >> 1, dx = wv & 1;
  const int NXT = 1 + dx;
  const int KS2 = ((1 + dy) * (1 + dx) * CIN) / 32;
  const int koff = (dy ? (dx ? 5 : 3) : (dx ? 1 : 0)) * CIN;

  f4_t acc[MPW_P][NT] = {};
  for (int ks = 0; ks < KS2; ++ks) {
    const int tapi = (ks * 32) / CIN;
    const int cb = ((ks * 32) % CIN) / 8 + l4;
    const int ra = tapi / NXT, rb = tapi % NXT;
    bf8_t bf[NT];
#pragma unroll
    for (int nt = 0; nt < NT; ++nt)
      bf[nt] = *(const bf8_t*)&wbp[(size_t)(nt * 16 + l15) * 9 * CIN + koff + ks * 32 + 8 * l4];
#pragma unroll
    for (int mi = 0; mi < MPW_P; ++mi) {
      int m = mi * 16 + l15;
      int i = m / SW, j = m % SW;
      bf8_t a = *(const bf8_t*)&lds[(size_t)(((i + ra) * CG + cb) * TIW + (j + rb)) * 8];
#pragma unroll
      for (int nt = 0; nt < NT; ++nt)
        acc[mi][nt] = __builtin_amdgcn_mfma_f32_16x16x32_bf16(a, bf[nt], acc[mi][nt], 0, 0, 0);
    }
  }

#pragma unroll
  for (int mi = 0; mi < MPW_P; ++mi) {
#pragma unroll
    for (int nt = 0; nt < NT; ++nt) {
      int co = nt * 16 + l15;
      float bv = bias[co];
#pragma unroll
      for (int r = 0; r < 4; ++r) {
        int m = mi * 16 + l4 * 4 + r;
        int i = m / SW, j = m % SW;
        int orow = 2 * (ty0s + i) + dy, ocol = 2 * (tx0s + j) + dx;
        float v = acc[mi][nt][r] + bv;
        out[(((size_t)n * HO + orow) * WO + ocol) * COUT + co] = f2bf(gelu_f(v));
      }
    }
  }
  __syncthreads();
}

template<int CIN, int COUT, int HIN, int WIN, int SH, int SW>
__global__ __launch_bounds__(256) void tconvp_k(
    const us* __restrict__ in, const us* __restrict__ wbp,
    const float* __restrict__ bias, us* __restrict__ out)
{
  __shared__ us lds[(SH + 1) * (SW + 1) * (CIN / 8) * 8];
  tconvp_tile<CIN, COUT, HIN, WIN, SH, SW>(in, wbp, bias, out, blockIdx.x, 0, lds);
}

// ---------------------------------------------------------------------------
// MFMA GEMM. OUTMODE 3 = direct frag-swizzled (meffb) write (verified R22).
// ---------------------------------------------------------------------------
template<int BIASMODE, bool GELU, int OUTMODE>
__global__ __launch_bounds__(256) void gemm16_k(
    const us* __restrict__ A, const us* __restrict__ Bw,
    const float* __restrict__ bias, void* __restrict__ Cv, int M, int N, int K)
{
  const int lane = threadIdx.x & 63, wv = threadIdx.x >> 6;
  const int l15 = lane & 15, l4 = lane >> 4;
  const int mbase = blockIdx.y * 64 + wv * 16;
  const int nbase = blockIdx.x * 64;
  f4_t acc[4] = {};
  for (int k0 = 0; k0 < K; k0 += 32) {
    bf8_t a = *(const bf8_t*)&A[(size_t)(mbase + l15) * K + k0 + 8 * l4];
#pragma unroll
    for (int nt = 0; nt < 4; ++nt) {
      bf8_t b = *(const bf8_t*)&Bw[(size_t)(nbase + nt * 16 + l15) * K + k0 + 8 * l4];
      acc[nt] = __builtin_amdgcn_mfma_f32_16x16x32_bf16(a, b, acc[nt], 0, 0, 0);
    }
  }
#pragma unroll
  for (int nt = 0; nt < 4; ++nt) {
    int col = nbase + nt * 16 + l15;
    float bv = 0.f;
    if (BIASMODE == 0) bv = bias[col];
    if (BIASMODE == 1) bv = bias[(col & 63) * 64 + (col >> 6)];
#pragma unroll
    for (int r = 0; r < 4; ++r) {
      int row = mbase + l4 * 4 + r;
      float v = acc[nt][r] + bv;
      if (GELU) v = gelu_f(v);
      if (OUTMODE == 0)      ((float*)Cv)[(size_t)row * N + col] = v;
      else if (OUTMODE == 1) ((us*)Cv)[(size_t)row * N + col] = f2bf(v);
      else if (OUTMODE == 2) {
        int orow = (row & 31) * 16 + (row >> 5);   // b*16 + tt
        ((us*)Cv)[(size_t)orow * N + col] = f2bf(v);
      } else {
        int nt2 = row >> 4, l15d = row & 15;
        int ks2 = col >> 5, l4d = (col >> 3) & 3, e2 = col & 7;
        ((us*)Cv)[(size_t)nt2 * 4096 + ks2 * 512 + (l4d * 16 + l15d) * 8 + e2] = f2bf(v);
      }
    }
  }
}

// el GEMM split-K: M=512, K=4096 in 8 chunks of 512. grid (4,8,8). fp32 partials.
__global__ __launch_bounds__(256) void elgemm_splitk_k(
    const us* __restrict__ A, const us* __restrict__ Bw,
    float* __restrict__ zpart)
{
  const int lane = threadIdx.x & 63, wv = threadIdx.x >> 6;
  const int l15 = lane & 15, l4 = lane >> 4;
  const int mbase = blockIdx.y * 64 + wv * 16;
  const int nbase = blockIdx.x * 64;
  const int kbase = blockIdx.z * 512;
  f4_t acc[4] = {};
  for (int k0 = kbase; k0 < kbase + 512; k0 += 32) {
    bf8_t a = *(const bf8_t*)&A[(size_t)(mbase + l15) * 4096 + k0 + 8 * l4];
#pragma unroll
    for (int nt = 0; nt < 4; ++nt) {
      bf8_t b = *(const bf8_t*)&Bw[(size_t)(nbase + nt * 16 + l15) * 4096 + k0 + 8 * l4];
      acc[nt] = __builtin_amdgcn_mfma_f32_16x16x32_bf16(a, b, acc[nt], 0, 0, 0);
    }
  }
  float* zp = zpart + (size_t)blockIdx.z * 131072;
#pragma unroll
  for (int nt = 0; nt < 4; ++nt) {
    int col = nbase + nt * 16 + l15;
#pragma unroll
    for (int r = 0; r < 4; ++r) {
      int row = mbase + l4 * 4 + r;
      zp[(size_t)row * 256 + col] = acc[nt][r];
    }
  }
}

// combine split-K partials (fixed order = deterministic) + bias.
__global__ __launch_bounds__(256) void zcombine_k(
    const float* __restrict__ zpart, const float* __restrict__ el_b,
    us* __restrict__ zbf, us* __restrict__ ydec)
{
  int idx = blockIdx.x * 256 + threadIdx.x;   // < 131072
  int row = idx >> 8, col = idx & 255;        // row = b*16+tt
  float s = el_b[col];
#pragma unroll
  for (int kc = 0; kc < 8; ++kc) s += zpart[(size_t)kc * 131072 + idx];
  int b = row >> 4, tt = row & 15;
  us v = f2bf(s);
  zbf[(size_t)(tt * 32 + b) * 256 + col] = v;
  ydec[(size_t)(512 + row) * 256 + col] = v;
}

// dl GEMM tile: rows rofs..rofs+511, dl-permuted bias, gelu, bf16
DEV void dlgemm_tile(const us* __restrict__ A, const us* __restrict__ Bw,
                     const float* __restrict__ bias, us* __restrict__ C,
                     int vb, int rofs)
{
  const int lane = threadIdx.x & 63, wv = threadIdx.x >> 6;
  const int l15 = lane & 15, l4 = lane >> 4;
  const int mbase = rofs + (vb >> 6) * 64 + wv * 16;
  const int nbase = (vb & 63) * 64;
  f4_t acc[4] = {};
  for (int k0 = 0; k0 < 256; k0 += 32) {
    bf8_t a = *(const bf8_t*)&A[(size_t)(mbase + l15) * 256 + k0 + 8 * l4];
#pragma unroll
    for (int nt = 0; nt < 4; ++nt) {
      bf8_t b = *(const bf8_t*)&Bw[(size_t)(nbase + nt * 16 + l15) * 256 + k0 + 8 * l4];
      acc[nt] = __builtin_amdgcn_mfma_f32_16x16x32_bf16(a, b, acc[nt], 0, 0, 0);
    }
  }
#pragma unroll
  for (int nt = 0; nt < 4; ++nt) {
    int col = nbase + nt * 16 + l15;
    float bv = bias[(col & 63) * 64 + (col >> 6)];
#pragma unroll
    for (int r = 0; r < 4; ++r) {
      int row = mbase + l4 * 4 + r;
      C[(size_t)row * 4096 + col] = f2bf(gelu_f(acc[nt][r] + bv));
    }
  }
}

// dt3 tile (device fn): PRED=1 -> n=nl, store fout, compare ref(=t);
// PRED=0 -> n=512+nl, compare ref(=x). partials[(PRED?0:2048)+vb].
template<int PRED>
DEV void dt3_tile(const us* __restrict__ in, const float* __restrict__ w,
                  const float* __restrict__ bias, const float* __restrict__ ref,
                  float* __restrict__ fout, float* __restrict__ partials,
                  int vb, float* sw, float* ws4)
{
  for (int i2 = threadIdx.x; i2 < 288; i2 += 256) sw[i2] = w[i2];
  __syncthreads();
  int idx = vb * 256 + threadIdx.x;
  int j = idx & 31, i = (idx >> 5) & 31, nl = idx >> 10;   // nl 0..511
  int n = PRED ? nl : (512 + nl);
  bool okj = (j < 31), oki = (i < 31);
  const us* r00 = in + (((size_t)n * 32 + i) * 32 + j) * 32;
  const us* r01 = r00 + 32;
  const us* r10 = r00 + 1024;
  const us* r11 = r10 + 32;
  float b0 = bias[0];
  float acc00 = b0, acc01 = b0, acc10 = b0, acc11 = b0;
  uint4 z4 = {0, 0, 0, 0};
#pragma unroll
  for (int g2 = 0; g2 < 4; ++g2) {
    uint4 v00 = *(const uint4*)&r00[g2 * 8];
    uint4 v01 = okj ? *(const uint4*)&r01[g2 * 8] : z4;
    uint4 v10 = oki ? *(const uint4*)&r10[g2 * 8] : z4;
    uint4 v11 = (oki && okj) ? *(const uint4*)&r11[g2 * 8] : z4;
    unsigned a00[4] = {v00.x, v00.y, v00.z, v00.w};
    unsigned a01[4] = {v01.x, v01.y, v01.z, v01.w};
    unsigned a10[4] = {v10.x, v10.y, v10.z, v10.w};
    unsigned a11[4] = {v11.x, v11.y, v11.z, v11.w};
#pragma unroll
    for (int h2 = 0; h2 < 4; ++h2) {
      int c0 = (g2 * 8 + h2 * 2) * 9;
      float xl, xh;
      xl = __uint_as_float(a00[h2] << 16); xh = __uint_as_float(a00[h2] & 0xffff0000u);
      acc00 = fmaf(xl, sw[c0 + 4], acc00); acc00 = fmaf(xh, sw[c0 + 13], acc00);
      acc01 = fmaf(xl, sw[c0 + 5], acc01); acc01 = fmaf(xh, sw[c0 + 14], acc01);
      acc10 = fmaf(xl, sw[c0 + 7], acc10); acc10 = fmaf(xh, sw[c0 + 16], acc10);
      acc11 = fmaf(xl, sw[c0 + 8], acc11); acc11 = fmaf(xh, sw[c0 + 17], acc11);
      xl = __uint_as_float(a01[h2] << 16); xh = __uint_as_float(a01[h2] & 0xffff0000u);
      acc01 = fmaf(xl, sw[c0 + 3], acc01); acc01 = fmaf(xh, sw[c0 + 12], acc01);
      acc11 = fmaf(xl, sw[c0 + 6], acc11); acc11 = fmaf(xh, sw[c0 + 15], acc11);
      xl = __uint_as_float(a10[h2] << 16); xh = __uint_as_float(a10[h2] & 0xffff0000u);
      acc10 = fmaf(xl, sw[c0 + 1], acc10); acc10 = fmaf(xh, sw[c0 + 10], acc10);
      acc11 = fmaf(xl, sw[c0 + 2], acc11); acc11 = fmaf(xh, sw[c0 + 11], acc11);
      xl = __uint_as_float(a11[h2] << 16); xh = __uint_as_float(a11[h2] & 0xffff0000u);
      acc11 = fmaf(xl, sw[c0 + 0], acc11); acc11 = fmaf(xh, sw[c0 + 9], acc11);
    }
  }
  float o00 = tanh_f(acc00), o01 = tanh_f(acc01);
  float o10 = tanh_f(acc10), o11 = tanh_f(acc11);
  size_t px = (size_t)(2 * i) * 64 + 2 * j;
  if (PRED) {
    float* fb = fout + (size_t)nl * 4096;
    fb[px] = o00;      fb[px + 1] = o01;
    fb[px + 64] = o10; fb[px + 65] = o11;
  }
  const float* rr = ref + (size_t)nl * 4096;
  float d0 = o00 - rr[px],      d1 = o01 - rr[px + 1];
  float d2 = o10 - rr[px + 64], d3 = o11 - rr[px + 65];
  float s = d0 * d0 + d1 * d1 + d2 * d2 + d3 * d3;
#pragma unroll
  for (int off = 32; off > 0; off >>= 1) s += __shfl_down(s, off);
  if ((threadIdx.x & 63) == 0) ws4[threadIdx.x >> 6] = s;
  __syncthreads();
  if (threadIdx.x == 0) partials[(PRED ? 0 : 2048) + vb] = ws4[0] + ws4[1] + ws4[2] + ws4[3];
  __syncthreads();
}

// dt3 pred standalone (writes fout + partials[0..2047])
__global__ __launch_bounds__(256) void dt3_loss_k(
    const us* __restrict__ in, const float* __restrict__ w,
    const float* __restrict__ bias, const float* __restrict__ tref,
    float* __restrict__ fout, float* __restrict__ partials)
{
  __shared__ float sw[288];
  __shared__ float ws4[4];
  for (int i2 = threadIdx.x; i2 < 288; i2 += 256) sw[i2] = w[i2];
  __syncthreads();
  int idx = blockIdx.x * 256 + threadIdx.x;   // < 524288 (grid 2048)
  int j = idx & 31, i = (idx >> 5) & 31, n = idx >> 10;  // n 0..511
  bool okj = (j < 31), oki = (i < 31);
  const us* r00 = in + (((size_t)n * 32 + i) * 32 + j) * 32;
  const us* r01 = r00 + 32;
  const us* r10 = r00 + 1024;
  const us* r11 = r10 + 32;
  float b0 = bias[0];
  float acc00 = b0, acc01 = b0, acc10 = b0, acc11 = b0;
  uint4 z4 = {0, 0, 0, 0};
#pragma unroll
  for (int g2 = 0; g2 < 4; ++g2) {
    uint4 v00 = *(const uint4*)&r00[g2 * 8];
    uint4 v01 = okj ? *(const uint4*)&r01[g2 * 8] : z4;
    uint4 v10 = oki ? *(const uint4*)&r10[g2 * 8] : z4;
    uint4 v11 = (oki && okj) ? *(const uint4*)&r11[g2 * 8] : z4;
    unsigned a00[4] = {v00.x, v00.y, v00.z, v00.w};
    unsigned a01[4] = {v01.x, v01.y, v01.z, v01.w};
    unsigned a10[4] = {v10.x, v10.y, v10.z, v10.w};
    unsigned a11[4] = {v11.x, v11.y, v11.z, v11.w};
#pragma unroll
    for (int h2 = 0; h2 < 4; ++h2) {
      int c0 = (g2 * 8 + h2 * 2) * 9;
      float xl, xh;
      xl = __uint_as_float(a00[h2] << 16); xh = __uint_as_float(a00[h2] & 0xffff0000u);
      acc00 = fmaf(xl, sw[c0 + 4], acc00); acc00 = fmaf(xh, sw[c0 + 13], acc00);
      acc01 = fmaf(xl, sw[c0 + 5], acc01); acc01 = fmaf(xh, sw[c0 + 14], acc01);
      acc10 = fmaf(xl, sw[c0 + 7], acc10); acc10 = fmaf(xh, sw[c0 + 16], acc10);
      acc11 = fmaf(xl, sw[c0 + 8], acc11); acc11 = fmaf(xh, sw[c0 + 17], acc11);
      xl = __uint_as_float(a01[h2] << 16); xh = __uint_as_float(a01[h2] & 0xffff0000u);
      acc01 = fmaf(xl, sw[c0 + 3], acc01); acc01 = fmaf(xh, sw[c0 + 12], acc01);
      acc11 = fmaf(xl, sw[c0 + 6], acc11); acc11 = fmaf(xh, sw[c0 + 15], acc11);
      xl = __uint_as_float(a10[h2] << 16); xh = __uint_as_float(a10[h2] & 0xffff0000u);
      acc10 = fmaf(xl, sw[c0 + 1], acc10); acc10 = fmaf(xh, sw[c0 + 10], acc10);
      acc11 = fmaf(xl, sw[c0 + 2], acc11); acc11 = fmaf(xh, sw[c0 + 11], acc11);
      xl = __uint_as_float(a11[h2] << 16); xh = __uint_as_float(a11[h2] & 0xffff0000u);
      acc11 = fmaf(xl, sw[c0 + 0], acc11); acc11 = fmaf(xh, sw[c0 + 9], acc11);
    }
  }
  float o00 = tanh_f(acc00), o01 = tanh_f(acc01);
  float o10 = tanh_f(acc10), o11 = tanh_f(acc11);
  size_t px = (size_t)(2 * i) * 64 + 2 * j;
  float* fb = fout + (size_t)n * 4096;
  fb[px] = o00;      fb[px + 1] = o01;
  fb[px + 64] = o10; fb[px + 65] = o11;
  const float* tr = tref + (size_t)n * 4096;
  float d0 = o00 - tr[px],      d1 = o01 - tr[px + 1];
  float d2 = o10 - tr[px + 64], d3 = o11 - tr[px + 65];
  float s = d0 * d0 + d1 * d1 + d2 * d2 + d3 * d3;
#pragma unroll
  for (int off = 32; off > 0; off >>= 1) s += __shfl_down(s, off);
  if ((threadIdx.x & 63) == 0) ws4[threadIdx.x >> 6] = s;
  __syncthreads();
  if (threadIdx.x == 0) partials[blockIdx.x] = ws4[0] + ws4[1] + ws4[2] + ws4[3];
}

__global__ __launch_bounds__(256) void loss_final_k(
    const float* __restrict__ partials, float* __restrict__ out01)
{
  __shared__ float red[256];
  int base = blockIdx.x * 2048;        // block 0: pred, block 1: rec
  float s = 0.f;
  for (int i = threadIdx.x; i < 2048; i += 256) s += partials[base + i];
  red[threadIdx.x] = s;
  __syncthreads();
#pragma unroll
  for (int st = 128; st > 0; st >>= 1) {
    if (threadIdx.x < st) red[threadIdx.x] += red[threadIdx.x + st];
    __syncthreads();
  }
  if (threadIdx.x == 0) out01[blockIdx.x] = red[0] * (1.0f / 2097152.0f);
}

// outs-GEMM standalone (pred ydec rows, permuted): grid (4,8)
__global__ __launch_bounds__(256) void outsgemm_k(
    const us* __restrict__ A, const us* __restrict__ Bw,
    const float* __restrict__ bias, us* __restrict__ ydec)
{
  const int lane = threadIdx.x & 63, wv = threadIdx.x >> 6;
  const int l15 = lane & 15, l4 = lane >> 4;
  const int mbase = blockIdx.y * 64 + wv * 16;
  const int nbase = blockIdx.x * 64;
  f4_t acc[4] = {};
  for (int k0 = 0; k0 < 256; k0 += 32) {
    bf8_t a = *(const bf8_t*)&A[(size_t)(mbase + l15) * 256 + k0 + 8 * l4];
#pragma unroll
    for (int nt = 0; nt < 4; ++nt) {
      bf8_t b = *(const bf8_t*)&Bw[(size_t)(nbase + nt * 16 + l15) * 256 + k0 + 8 * l4];
      acc[nt] = __builtin_amdgcn_mfma_f32_16x16x32_bf16(a, b, acc[nt], 0, 0, 0);
    }
  }
#pragma unroll
  for (int nt = 0; nt < 4; ++nt) {
    int col = nbase + nt * 16 + l15;
    float bv = bias[col];
#pragma unroll
    for (int r = 0; r < 4; ++r) {
      int row = mbase + l4 * 4 + r;
      int orow = (row & 31) * 16 + (row >> 5);   // b*16 + tt
      ydec[(size_t)orow * 256 + col] = f2bf(acc[nt][r] + bv);
    }
  }
}

// dl pred standalone: grid (64,8), rows 0..511
__global__ __launch_bounds__(256) void dlgemm_pred_k(
    const us* __restrict__ A, const us* __restrict__ Bw,
    const float* __restrict__ bias, us* __restrict__ C)
{
  dlgemm_tile(A, Bw, bias, C, (int)(blockIdx.y * 64 + blockIdx.x), 0);
}

// ---------------------------------------------------------------------------
// MEGA kernel: blocks 0..159 = LSTM; 160..255 = rec-half decoder.
// ---------------------------------------------------------------------------
#define LSTM_NB 160

DEV void gridbar(unsigned* bar, unsigned target) {
  __syncthreads();
  if (threadIdx.x == 0) {
    __hip_atomic_fetch_add(bar, 1u, __ATOMIC_RELEASE, __HIP_MEMORY_SCOPE_AGENT);
    unsigned spins = 0;
    while (__hip_atomic_load(bar, __ATOMIC_RELAXED, __HIP_MEMORY_SCOPE_AGENT) < target) {
      __builtin_amdgcn_s_sleep(2);
      if (++spins > (1u << 24)) break;   // safety valve
    }
    (void)__hip_atomic_load(bar, __ATOMIC_ACQUIRE, __HIP_MEMORY_SCOPE_AGENT);
  }
  __syncthreads();
}

DEV void spin_min16s(unsigned* f, unsigned tgt) {
  if ((int)tgt <= 0) return;
  unsigned spins = 0;
  for (;;) {
    unsigned m = 0xffffffffu;
#pragma unroll
    for (int i = 0; i < 16; ++i) {
      unsigned v = __hip_atomic_load(f + i * 32, __ATOMIC_RELAXED, __HIP_MEMORY_SCOPE_AGENT);
      m = v < m ? v : m;
    }
    if (m >= tgt) return;
    if (++spins > (1u << 22)) return;    // safety valve
  }
}

__global__ __launch_bounds__(256, 1) void mega_k(
    const float* __restrict__ Wih,
    const float* __restrict__ Whh, const us* __restrict__ meffb,
    const float* __restrict__ bih, const float* __restrict__ bhh,
    const float* __restrict__ beff,
    const us* __restrict__ zbf, us* __restrict__ hbf, us* __restrict__ h9sav,
    unsigned* __restrict__ bar,
    const us* __restrict__ ydec, const us* __restrict__ dlWb,
    const float* __restrict__ dl_b,
    const us* __restrict__ wbp_dt1, const float* __restrict__ dt1_b,
    const us* __restrict__ wb_dc1,  const float* __restrict__ dc1_b,
    const us* __restrict__ wbp_dt2, const float* __restrict__ dt2_b,
    const us* __restrict__ wb_dc2,  const float* __restrict__ dc2_b,
    const float* __restrict__ dt3_w, const float* __restrict__ dt3_b,
    const float* __restrict__ xref,
    us* __restrict__ bufA, us* __restrict__ bufB,
    float* __restrict__ partials)
{
  __shared__ __align__(16) unsigned char smem[109568];

  const int tid = threadIdx.x;
  const int bid = blockIdx.x;

  if (bid < 160) {
    // ================= LSTM path =========================================
    us*    s_w   = (us*)smem;                      // 65536 B
    us*    s_x   = (us*)(smem + 65536);            // 16384 B
    us*    s_h   = (us*)(smem + 81920);            // 16384 B
    float* zsm   = (float*)(smem + 98304);         // 8704 B
    float* cls   = (float*)(smem + 107008);        // 2048 B
    float* sbias = (float*)(smem + 109056);        // 256 B
    float* sb2   = (float*)(smem + 109312);        // 256 B

    const int l   = bid >> 4;
    const int jg  = bid & 15;
    const int col0 = jg * 16;
    const int lane = tid & 63, g = tid >> 6;
    const int l15 = lane & 15, l4 = lane >> 4;
    const int gtid = bid * 256 + tid;

    unsigned* fl = bar + 64;
    unsigned* fown = fl + (size_t)l * 16 * 32;

    for (int i = gtid; i < 81920; i += LSTM_NB * 256) hbf[81920 + i] = 0;
    // stage weights: direct fp32 -> bf16 frag conversion from Wih/Whh
    for (int c = tid; c < 4096; c += 256) {
      int gm = c >> 9;                 // g*2 + m
      int gg = gm >> 1, m = gm & 1;
      int c2 = c & 511;
      int ks = c2 >> 6, ln = c2 & 63;
      const float* src = (m == 0 ? Wih : Whh)
          + ((size_t)l * 1024 + gg * 256 + jg * 16 + (ln & 15)) * 256
          + ks * 32 + (ln >> 4) * 8;
      us tmp[8];
#pragma unroll
      for (int e = 0; e < 8; ++e) tmp[e] = f2bf(src[e]);
      *(int4*)&s_w[(size_t)c * 8] = *(int4*)tmp;
    }
    for (int i = tid; i < 512; i += 256) cls[i] = 0.f;
    if (tid < 64) {
      int gg = tid >> 4, j = tid & 15;
      sbias[tid] = bih[l * 1024 + gg * 256 + col0 + j]
                 + bhh[l * 1024 + gg * 256 + col0 + j];
      sb2[tid]   = beff[gg * 256 + col0 + j] + bhh[gg * 256 + col0 + j];
    }

    gridbar(bar, LSTM_NB);

    for (int t = 0; t <= 30; ++t) {
      const int cur = t & 1, prv = cur ^ 1;
      const bool p2 = (t >= 16);
      const bool p2l0 = p2 && (l == 0);

      if (tid == 0) {
        spin_min16s(fown, (unsigned)t);
        (void)__hip_atomic_load(fown, __ATOMIC_ACQUIRE, __HIP_MEMORY_SCOPE_AGENT);
      }
      __syncthreads();
      const us* hb = hbf + (size_t)((prv * 10 + l) * 32) * 256;
#pragma unroll
      for (int i = 0; i < 4; ++i) {
        int c = tid + i * 256;
        int sw = (c & ~31) | ((c & 31) ^ ((c >> 5) & 7));
        *(int4*)&s_h[(size_t)sw * 8] = *(const int4*)&hb[(size_t)c * 8];
      }
      if (tid == 0) {
        if (l == 0) {
          if (t >= 16) spin_min16s(fl + (size_t)9 * 16 * 32, (unsigned)t);
        } else {
          spin_min16s(fl + (size_t)(l - 1) * 16 * 32, (unsigned)(t + 1));
        }
        if (t >= 2) {
          if (l < 9) spin_min16s(fl + (size_t)(l + 1) * 16 * 32, (unsigned)(t - 1));
          else if (t >= 17) spin_min16s(fl, (unsigned)t);
        }
        (void)__hip_atomic_load(fown, __ATOMIC_ACQUIRE, __HIP_MEMORY_SCOPE_AGENT);
      }
      __syncthreads();
      const us* xb =
          (l == 0) ? (p2 ? (hbf + (size_t)((prv * 10 + 9) * 32) * 256)
                         : (zbf + (size_t)t * 32 * 256))
                   : (hbf + (size_t)((cur * 10 + l - 1) * 32) * 256);
#pragma unroll
      for (int i = 0; i < 4; ++i) {
        int c = tid + i * 256;
        int sw = (c & ~31) | ((c & 31) ^ ((c >> 5) & 7));
        *(int4*)&s_x[(size_t)sw * 8] = *(const int4*)&xb[(size_t)c * 8];
      }
      __syncthreads();
      f4_t a0 = {}, a1 = {}, b0 = {}, b1 = {};
#pragma unroll
      for (int ks = 0; ks < 8; ++ks) {
        bf8_t bwi = *(const bf8_t*)&s_w[(size_t)((g * 2 + 0) * 4096 + ks * 512 + lane * 8)];
        bf8_t bwh = *(const bf8_t*)&s_w[(size_t)((g * 2 + 1) * 4096 + ks * 512 + lane * 8)];
        int cx0 = (l15 << 5) | ((ks * 4 + l4) ^ (l15 & 7));
        int cx1 = ((16 + l15) << 5) | ((ks * 4 + l4) ^ (l15 & 7));
        bf8_t ax0 = *(const bf8_t*)&s_x[(size_t)cx0 * 8];
        bf8_t ax1 = *(const bf8_t*)&s_x[(size_t)cx1 * 8];
        bf8_t ah0 = *(const bf8_t*)&s_h[(size_t)cx0 * 8];
        bf8_t ah1 = *(const bf8_t*)&s_h[(size_t)cx1 * 8];
        a0 = __builtin_amdgcn_mfma_f32_16x16x32_bf16(ax0, bwi, a0, 0, 0, 0);
        a1 = __builtin_amdgcn_mfma_f32_16x16x32_bf16(ax1, bwi, a1, 0, 0, 0);
        b0 = __builtin_amdgcn_mfma_f32_16x16x32_bf16(ah0, bwh, b0, 0, 0, 0);
        b1 = __builtin_amdgcn_mfma_f32_16x16x32_bf16(ah1, bwh, b1, 0, 0, 0);
      }
#pragma unroll
      for (int r = 0; r < 4; ++r) {
        zsm[(g * 32 + l4 * 4 + r) * 17 + l15] = a0[r] + b0[r];
        zsm[(g * 32 + 16 + l4 * 4 + r) * 17 + l15] = a1[r] + b1[r];
      }
      __syncthreads();
#pragma unroll
      for (int half = 0; half < 2; ++half) {
        int e = tid + half * 256;
        int b = e >> 4, j = e & 15;
        float zi = zsm[(0 * 32 + b) * 17 + j] + (p2l0 ? sb2[j]      : sbias[j]);
        float zf = zsm[(1 * 32 + b) * 17 + j] + (p2l0 ? sb2[16 + j] : sbias[16 + j]);
        float zg = zsm[(2 * 32 + b) * 17 + j] + (p2l0 ? sb2[32 + j] : sbias[32 + j]);
        float zo = zsm[(3 * 32 + b) * 17 + j] + (p2l0 ? sb2[48 + j] : sbias[48 + j]);
        float cold = cls[b * 16 + j];
        float cn = sigm_f(zf) * cold + sigm_f(zi) * tanh_f(zg);
        cls[b * 16 + j] = cn;
        float hn = sigm_f(zo) * tanh_f(cn);
        float hn_hi = __shfl_down(hn, 1);
        if (!(j & 1)) {
          unsigned pk = (unsigned)f2bf(hn) | ((unsigned)f2bf(hn_hi) << 16);
          astore((unsigned*)&hbf[(size_t)((cur * 10 + l) * 32 + b) * 256 + col0 + j], pk);
          if (l == 9 && t >= 15)
            astore((unsigned*)&h9sav[(size_t)((t - 15) * 32 + b) * 256 + col0 + j], pk);
        }
      }
      __syncthreads();
      if (tid == 0)
        __hip_atomic_store(&fown[jg * 32], (unsigned)(t + 1),
                           __ATOMIC_RELEASE, __HIP_MEMORY_SCOPE_AGENT);
      if (l == 0 && t == 15) {
        for (int c = tid; c < 2048; c += 256) {
          int gg = c >> 9, c2 = c & 511;
          const us* src = meffb + ((size_t)(gg * 16 + jg) * 8) * 512;
          *(int4*)&s_w[(size_t)((gg * 2) * 512 + c2) * 8] = *(const int4*)&src[(size_t)c2 * 8];
        }
        __syncthreads();
      }
    }
  } else {
    // ================= rec-half decoder path (96 blocks) ==================
    us* lds = (us*)smem;
    float* swq = (float*)(smem + 49152);
    float* ws4 = (float*)(smem + 50432);
    unsigned* bar96 = bar + 32;
    const int wg = bid - 160;
    int ep2 = 0;

    for (int vb = wg; vb < 512; vb += 96)
      dlgemm_tile(ydec, dlWb, dl_b, bufB, vb, 512);
    ++ep2; gridbar(bar96, (unsigned)(ep2 * 96));
    for (int vb = wg; vb < 512; vb += 96)
      tconvp_tile<64, 64, 8, 8, 8, 8>(bufB, wbp_dt1, dt1_b, bufA, vb, 512, lds);
    ++ep2; gridbar(bar96, (unsigned)(ep2 * 96));
    for (int vb = wg; vb < 512; vb += 96)
      convmf_tile<64, 64, 16, 16, 16, 16, 0>(bufA, wb_dc1, dc1_b, bufB, vb, 512, lds);
    ++ep2; gridbar(bar96, (unsigned)(ep2 * 96));
    for (int vb = wg; vb < 1024; vb += 96)
      tconvp_tile<64, 32, 16, 16, 8, 16>(bufB, wbp_dt2, dt2_b, bufA, vb, 512, lds);
    ++ep2; gridbar(bar96, (unsigned)(ep2 * 96));
    for (int vb = wg; vb < 2048; vb += 96)
      convmf_tile<32, 32, 32, 32, 16, 16, 0>(bufA, wb_dc2, dc2_b, bufB, vb, 512, lds);
    ++ep2; gridbar(bar96, (unsigned)(ep2 * 96));
    for (int vb = wg; vb < 2048; vb += 96)
      dt3_tile<0>(bufB, dt3_w, dt3_b, xref, (float*)0, partials, vb, swq, ws4);
  }
}

// ---------------------------------------------------------------------------
extern "C" void kernel_launch(void* const* d_in, const int* in_sizes, int n_in,
                              void* d_out, int out_size, void* d_ws, size_t ws_size,
                              hipStream_t stream) {
  const float* x     = (const float*)d_in[0];
  const float* t     = (const float*)d_in[1];
  const float* ec1_w = (const float*)d_in[2];
  const float* ec1_b = (const float*)d_in[3];
  const float* ec2_w = (const float*)d_in[4];
  const float* ec2_b = (const float*)d_in[5];
  const float* ec3_w = (const float*)d_in[6];
  const float* ec3_b = (const float*)d_in[7];
  const float* ec4_w = (const float*)d_in[8];
  const float* ec4_b = (const float*)d_in[9];
  const float* ec5_w = (const float*)d_in[10];
  const float* ec5_b = (const float*)d_in[11];
  const float* el_w  = (const float*)d_in[12];
  const float* el_b  = (const float*)d_in[13];
  const float* dl_w  = (const float*)d_in[14];
  const float* dl_b  = (const float*)d_in[15];
  const float* dt1_w = (const float*)d_in[16];
  const float* dt1_b = (const float*)d_in[17];
  const float* dc1_w = (const float*)d_in[18];
  const float* dc1_b = (const float*)d_in[19];
  const float* dt2_w = (const float*)d_in[20];
  const float* dt2_b = (const float*)d_in[21];
  const float* dc2_w = (const float*)d_in[22];
  const float* dc2_b = (const float*)d_in[23];
  const float* dt3_w = (const float*)d_in[24];
  const float* dt3_b = (const float*)d_in[25];
  const float* Wih   = (const float*)d_in[26];
  const float* Whh   = (const float*)d_in[27];
  const float* bih   = (const float*)d_in[28];
  const float* bhh   = (const float*)d_in[29];
  const float* lw    = (const float*)d_in[30];
  const float* lb    = (const float*)d_in[31];
  float* out = (float*)d_out;

  char* base = (char*)d_ws;
  size_t off = 0;
  auto alloc = [&](size_t bytes) -> char* {
    char* p = base + off;
    off += (bytes + 255) & ~(size_t)255;
    return p;
  };
  unsigned* bar   = (unsigned*)alloc(32768);
  float* zpart    = (float*)alloc((size_t)8 * 512 * 256 * 4);
  us*    zbf      = (us*)alloc((size_t)16 * 32 * 256 * 2);
  us*    hbf      = (us*)alloc((size_t)2 * 10 * 32 * 256 * 2);
  us*    h9sav    = (us*)alloc((size_t)16 * 32 * 256 * 2);
  us*    ydec     = (us*)alloc((size_t)1024 * 256 * 2);
  float* partials = (float*)alloc((size_t)16384 * 4);
  us* wb_ec2 = (us*)alloc((size_t)32 * 288 * 2);
  us* wb_ec3 = (us*)alloc((size_t)64 * 288 * 2);
  us* wb_ec4 = (us*)alloc((size_t)64 * 576 * 2);
  us* wb_ec5 = (us*)alloc((size_t)64 * 576 * 2);
  us* wbp_dt1 = (us*)alloc((size_t)64 * 576 * 2);
  us* wb_dc1 = (us*)alloc((size_t)64 * 576 * 2);
  us* wbp_dt2 = (us*)alloc((size_t)32 * 576 * 2);
  us* wb_dc2 = (us*)alloc((size_t)32 * 288 * 2);
  us* elWb   = (us*)alloc((size_t)256 * 4096 * 2);
  us* dlWb   = (us*)alloc((size_t)4096 * 256 * 2);
  us* wih0b  = (us*)alloc((size_t)1024 * 256 * 2);
  us* lwTb   = (us*)alloc((size_t)256 * 256 * 2);
  us* lwbp   = (us*)alloc((size_t)256 * 256 * 2);
  us* meffb  = (us*)alloc((size_t)1024 * 256 * 2);
  float* beff = (float*)alloc((size_t)1024 * 4);
  us* enc5   = (us*)alloc((size_t)512 * 4096 * 2);
  us* bufA   = (us*)alloc((size_t)1024 * 32 * 32 * 32 * 2);
  us* bufB   = (us*)alloc((size_t)1024 * 32 * 32 * 32 * 2);
  (void)in_sizes; (void)n_in; (void)out_size; (void)ws_size;

  hipMemsetAsync(bar, 0, 32768, stream);

  // ---- weight prep (fused) + meff direct frag write ----
  prep_all_k<<<10524, 256, 0, stream>>>(ec2_w, ec3_w, ec4_w, ec5_w,
                                        dt1_w, dc1_w, dt2_w, dc2_w,
                                        wb_ec2, wb_ec3, wb_ec4, wb_ec5,
                                        wbp_dt1, wb_dc1, wbp_dt2, wb_dc2,
                                        Wih, lw, lb, bih, wih0b, lwTb, lwbp, beff,
                                        el_w, dl_w, elWb, dlWb);
  gemm16_k<2, false, 3><<<dim3(4, 16), 256, 0, stream>>>(wih0b, lwTb, lb, meffb, 1024, 256, 256);

  // ---- encoder: x frames only (512 images) ----
  ec1_k<<<2048, 256, 0, stream>>>(x, ec1_w, ec1_b, bufA);
  convmf_k<32, 32, 32, 32, 16, 16, 0><<<2048, 256, 0, stream>>>(bufA, wb_ec2, ec2_b, bufB);
  convmf_k<32, 64, 32, 32, 16, 16, 1><<<512, 256, 0, stream>>>(bufB, wb_ec3, ec3_b, bufA);
  convmf_k<64, 64, 16, 16, 16, 16, 0><<<512, 256, 0, stream>>>(bufA, wb_ec4, ec4_b, bufB);
  convmf_k<64, 64, 16, 16, 8, 8, 1><<<512, 256, 0, stream>>>(bufB, wb_ec5, ec5_b, enc5);
  elgemm_splitk_k<<<dim3(4, 8, 8), 256, 0, stream>>>(enc5, elWb, zpart);
  zcombine_k<<<512, 256, 0, stream>>>(zpart, el_b, zbf, ydec);

  // ---- MEGA: LSTM (160 blocks) || rec-half decoder (96 blocks) ----
  mega_k<<<256, 256, 0, stream>>>(Wih, Whh, meffb, bih, bhh, beff,
                                  zbf, hbf, h9sav, bar,
                                  ydec, dlWb, dl_b,
                                  wbp_dt1, dt1_b, wb_dc1, dc1_b,
                                  wbp_dt2, dt2_b, wb_dc2, dc2_b,
                                  dt3_w, dt3_b, x, bufA, bufB, partials);

  // ---- pred ydec rows, then pred-half decoder (standalone, proven) ----
  outsgemm_k<<<dim3(4, 8), 256, 0, stream>>>(h9sav, lwbp, lb, ydec);
  dlgemm_pred_k<<<dim3(64, 8), 256, 0, stream>>>(ydec, dlWb, dl_b, bufB);
  tconvp_k<64, 64, 8, 8, 8, 8><<<512, 256, 0, stream>>>(bufB, wbp_dt1, dt1_b, bufA);
  convmf_k<64, 64, 16, 16, 16, 16, 0><<<512, 256, 0, stream>>>(bufA, wb_dc1, dc1_b, bufB);
  tconvp_k<64, 32, 16, 16, 8, 16><<<1024, 256, 0, stream>>>(bufB, wbp_dt2, dt2_b, bufA);
  convmf_k<32, 32, 32, 32, 16, 16, 0><<<2048, 256, 0, stream>>>(bufA, wb_dc2, dc2_b, bufB);
  dt3_loss_k<<<2048, 256, 0, stream>>>(bufB, dt3_w, dt3_b, t, out + 2, partials);
  loss_final_k<<<2, 256, 0, stream>>>(partials, out);
}